// Round 20
// baseline (745.929 us; speedup 1.0000x reference)
//
#include <hip/hip_runtime.h>
#include <hip/hip_bf16.h>
#include <hip/hip_fp16.h>

#define B_   16
#define N_   1024
#define KNN  20
#define NP   (B_ * N_)   // 16384

typedef short bf16x8 __attribute__((ext_vector_type(8)));
typedef _Float16 half8 __attribute__((ext_vector_type(8)));
typedef float f32x4  __attribute__((ext_vector_type(4)));
typedef float f32x16 __attribute__((ext_vector_type(16)));

__device__ __forceinline__ unsigned short f2bf(float f) {
  unsigned u = __float_as_uint(f);
  u += 0x7fffu + ((u >> 16) & 1u);   // RNE
  return (unsigned short)(u >> 16);
}

// Monotone float<->u32 map: order-preserving, so atomicMax(u32) == float max.
__device__ __forceinline__ unsigned fmap(float f) {
  unsigned u = __float_as_uint(f);
  return (u & 0x80000000u) ? ~u : (u | 0x80000000u);
}
__device__ __forceinline__ float funmap(unsigned k) {
  unsigned u = (k & 0x80000000u) ? (k & 0x7FFFFFFFu) : ~k;
  return __uint_as_float(u);
}

// ---------------------------------------------------------------------------
// FUSED PRELUDE: all input-only work in ONE dispatch.
//   blocks [0,2176):    pairdist (C=3, fp32 VALU) -- verified body
//   blocks [2176,3072): cvtall weight prep        -- verified body
//   blocks [3072,4096): transform1 (layer-1 u/v)  -- verified body
//   block  4096:        zero pooled (u32 min)
// ---------------------------------------------------------------------------
__global__ __launch_bounds__(256) void prelude_kernel(
    const float* __restrict__ pos, unsigned* __restrict__ Dk,
    const float* __restrict__ W0, const float* __restrict__ W1,
    const float* __restrict__ W2, const float* __restrict__ W3,
    unsigned short* __restrict__ o0, unsigned short* __restrict__ o1,
    unsigned short* __restrict__ o2, unsigned short* __restrict__ o3,
    const float* __restrict__ A2, const float* __restrict__ A3,
    const float* __restrict__ A4,
    unsigned short* __restrict__ d2, unsigned short* __restrict__ b2,
    unsigned short* __restrict__ d3, unsigned short* __restrict__ b3,
    unsigned short* __restrict__ d4, unsigned short* __restrict__ b4,
    const float* __restrict__ W1a, const float* __restrict__ b1a,
    unsigned short* __restrict__ u, unsigned short* __restrict__ v,
    unsigned* __restrict__ pooledU) {
  int blk = blockIdx.x;
  if (blk < 2176) {
    // ---------------- pairdist (C=3), verified body ----------------
    __shared__ __align__(16) char pd_smem[64 * 68 * 4];
    __shared__ float sqi_s[64], sqj_s[64];
    float (*Xi)[68] = (float(*)[68])pd_smem;
    float (*Xj)[68] = (float(*)[68])(pd_smem + 32 * 68 * 4);
    unsigned (*Tt)[68] = (unsigned(*)[68])pd_smem;
    const int LD = 3, coff = 0, C = 3;
    int lin = blk % 136, by = 0;
    int b = blk / 136;
    while (lin >= 16 - by) { lin -= 16 - by; ++by; }
    int bx = by + lin;
    int i0 = by * 64, j0 = bx * 64;
    int t  = threadIdx.x;
    int tx = t & 15, ty = t >> 4;
    int cx = t & 31, ry = t >> 5;
    float acc[4][4] = {};
    float sqacc = 0.f;
    for (int c0 = 0; c0 < C; c0 += 32) {
      int cc = min(32, C - c0);
      if (cx < cc) {
        for (int r = ry; r < 64; r += 8) {
          Xi[cx][r] = pos[(size_t)(b * N_ + i0 + r) * LD + coff + c0 + cx];
          Xj[cx][r] = pos[(size_t)(b * N_ + j0 + r) * LD + coff + c0 + cx];
        }
      }
      __syncthreads();
      if (t < 64) {
        for (int c = 0; c < cc; ++c) sqacc = fmaf(Xi[c][t], Xi[c][t], sqacc);
      } else if (t < 128) {
        int r = t - 64;
        for (int c = 0; c < cc; ++c) sqacc = fmaf(Xj[c][r], Xj[c][r], sqacc);
      }
      for (int c = 0; c < cc; ++c) {
        float4 a4 = *(const float4*)&Xi[c][ty * 4];
        float4 b4 = *(const float4*)&Xj[c][tx * 4];
        float a[4] = {a4.x, a4.y, a4.z, a4.w};
        float bb[4] = {b4.x, b4.y, b4.z, b4.w};
#pragma unroll
        for (int p = 0; p < 4; ++p)
#pragma unroll
          for (int q = 0; q < 4; ++q)
            acc[p][q] = fmaf(a[p], bb[q], acc[p][q]);
      }
      __syncthreads();
    }
    if (t < 64) sqi_s[t] = sqacc;
    else if (t < 128) sqj_s[t - 64] = sqacc;
    __syncthreads();
    float sqi[4], sqj[4];
#pragma unroll
    for (int p = 0; p < 4; ++p) sqi[p] = sqi_s[ty * 4 + p];
#pragma unroll
    for (int q = 0; q < 4; ++q) sqj[q] = sqj_s[tx * 4 + q];
    bool offdiag = (bx > by);
#pragma unroll
    for (int p = 0; p < 4; ++p) {
      uint4 st;
      unsigned* kk = (unsigned*)&st;
#pragma unroll
      for (int q = 0; q < 4; ++q) {
        float d = fmaxf((sqi[p] - 2.f * acc[p][q]) + sqj[q], 0.f);
        unsigned db = __float_as_uint(d) & 0xFFFFFC00u;
        kk[q] = db | (unsigned)(j0 + tx * 4 + q);
        if (offdiag)
          Tt[tx * 4 + q][ty * 4 + p] = db | (unsigned)(i0 + ty * 4 + p);
      }
      *(uint4*)&Dk[(size_t)(b * N_ + i0 + ty * 4 + p) * N_ + j0 + tx * 4] = st;
    }
    if (offdiag) {
      __syncthreads();
#pragma unroll
      for (int p = 0; p < 4; ++p) {
        *(uint4*)&Dk[(size_t)(b * N_ + j0 + ty * 4 + p) * N_ + i0 + tx * 4] =
            *(uint4*)&Tt[ty * 4 + p][tx * 4];
      }
    }
  } else if (blk < 3072) {
    // ---------------- cvtall, verified body (flattened grid) ----------------
    int t2 = blk - 2176;
    int gx = t2 & 15, gy = (t2 >> 4) & 7, z = t2 >> 7;
    if (z < 4) {
      __shared__ unsigned short tile[32][33];
      const float* W; unsigned short* out; int Cmid, Cout;
      if (z == 0)      { W = W0; out = o0; Cmid = 64;  Cout = 64;  }
      else if (z == 1) { W = W1; out = o1; Cmid = 64;  Cout = 64;  }
      else if (z == 2) { W = W2; out = o2; Cmid = 128; Cout = 128; }
      else             { W = W3; out = o3; Cmid = 256; Cout = 256; }
      int c0 = gx * 32, co0 = gy * 32;
      if (c0 >= Cmid || co0 >= Cout) return;
      int tx = threadIdx.x & 31, ty = threadIdx.x >> 5;   // 32 x 8
      for (int r = ty; r < 32; r += 8)
        tile[r][tx] = f2bf(W[(size_t)(c0 + r) * Cout + co0 + tx]);
      __syncthreads();
      for (int r = ty; r < 32; r += 8)
        out[(size_t)(co0 + r) * Cmid + c0 + tx] = tile[tx][r];
    } else {
      if (gy > 0) return;
      int zz = z - 4;
      const float* Wa; unsigned short *wd, *wb; int Cin, Cmid;
      if (zz == 0)      { Wa = A2; wd = d2; wb = b2; Cin = 64;  Cmid = 64;  }
      else if (zz == 1) { Wa = A3; wd = d3; wb = b3; Cin = 64;  Cmid = 128; }
      else              { Wa = A4; wd = d4; wb = b4; Cin = 128; Cmid = 256; }
      int KC = Cin / 16;
      int NC = (Cmid / 32) * KC * 64;
      int ci = gx * 256 + threadIdx.x;
      if (ci >= NC) return;
      int ntc = ci >> 6, lane = ci & 63;
      int nt = ntc / KC, c = ntc - nt * KC;
      int n  = nt * 32 + (lane & 31);
      int kb = c * 16 + (lane >> 5) * 8;
#pragma unroll
      for (int j = 0; j < 8; ++j) {
        float top = Wa[(size_t)(kb + j) * Cmid + n];
        float bot = Wa[(size_t)(Cin + kb + j) * Cmid + n];
        wd[(size_t)ci * 8 + j] = f2bf(top - bot);
        wb[(size_t)ci * 8 + j] = f2bf(bot);
      }
    }
  } else if (blk < 4096) {
    // ---------------- transform1 (layer 1, Cin=3), verified body ----------
    __shared__ float xs[48];
    constexpr int Cin = 3, Cmid = 64;
    int w = threadIdx.x >> 6, lane = threadIdx.x & 63;
    int m  = lane;
    int p0 = (blk - 3072) * 16;
    for (int i = threadIdx.x; i < 16 * Cin; i += 256) {
      int pt = i / Cin, c = i - pt * Cin;
      xs[pt * Cin + c] = pos[(size_t)(p0 + pt) * 3 + c];
    }
    __syncthreads();
    const float* xw = xs + (w * 4) * Cin;
    float ua[4] = {0.f, 0.f, 0.f, 0.f}, va[4] = {0.f, 0.f, 0.f, 0.f};
    for (int c = 0; c < Cin; ++c) {
      float wt = W1a[(size_t)c * Cmid + m];
      float wb = W1a[(size_t)(Cin + c) * Cmid + m];
      float wd = wt - wb;
#pragma unroll
      for (int i = 0; i < 4; ++i) {
        float xv = xw[i * Cin + c];
        ua[i] = fmaf(xv, wd, ua[i]);
        va[i] = fmaf(xv, wb, va[i]);
      }
    }
    float bias = b1a[m];
#pragma unroll
    for (int i = 0; i < 4; ++i) {
      u[(size_t)(p0 + w * 4 + i) * Cmid + m] = f2bf(ua[i] + bias);
      v[(size_t)(p0 + w * 4 + i) * Cmid + m] = f2bf(va[i]);
    }
  } else {
    // ---------------- zero pooled (u32 0 < fmap(-inf)) ----------
    for (int i = threadIdx.x; i < B_ * 512; i += 256) pooledU[i] = 0u;
  }
}

// ---------------------------------------------------------------------------
// MFMA Gram pairdist (layers 2-4). Verified rounds 11/14/16 (dual acc).
// ---------------------------------------------------------------------------
template<int C>
__global__ __launch_bounds__(256) void gramt_kernel(
    const float* __restrict__ X, int coff, unsigned* __restrict__ Dk) {
  constexpr int KP = C / 64;
  constexpr int F4 = C / 4;       // float4 per row
  __shared__ __align__(16) char gt_smem[32768];   // Phi|Plo|Qhi|Qlo / Tt overlay
  unsigned short* Phi = (unsigned short*)gt_smem;        // 8KB each
  unsigned short* Plo = Phi + 4096;
  unsigned short* Qhi = Plo + 4096;
  unsigned short* Qlo = Qhi + 4096;
  unsigned (*Tt)[68] = (unsigned(*)[68])gt_smem;         // 17.4KB overlay
  __shared__ float nrmI[64], nrmJ[64];                   // outside overlay
  int tid = threadIdx.x, wv = tid >> 6, lane = tid & 63;
  int rc = lane & 31, half = lane >> 5;
  int lin = blockIdx.x, ti = 0;
  while (lin >= 16 - ti) { lin -= 16 - ti; ++ti; }
  int tj = ti + lin;
  int b  = blockIdx.z;
  int qi = wv >> 1, qj = wv & 1;

  {
    int pr  = tid >> 1, sub = tid & 1;      // pr: 0..127
    int side = pr >> 6, row = pr & 63;
    int grow = b * N_ + (side ? tj : ti) * 64 + row;
    const float4* xr = (const float4*)(X + (size_t)grow * 512 + coff);
    float s = 0.f;
#pragma unroll
    for (int k = sub; k < F4; k += 2) {
      float4 x4 = xr[k];
      s = fmaf(x4.x, x4.x, s); s = fmaf(x4.y, x4.y, s);
      s = fmaf(x4.z, x4.z, s); s = fmaf(x4.w, x4.w, s);
    }
    s += __shfl_xor(s, 1);
    if (sub == 0) { if (side) nrmJ[row] = s; else nrmI[row] = s; }
  }

  f32x16 accA = {}, accB = {};
#pragma unroll
  for (int kp = 0; kp < KP; ++kp) {
    if (kp) __syncthreads();
#pragma unroll
    for (int it = 0; it < 4; ++it) {
      int u = tid + it * 256;
      int side = u >> 9;
      int row  = (u >> 3) & 63;
      int slot = u & 7;
      int grow = b * N_ + (side ? tj : ti) * 64 + row;
      const float* xr = X + (size_t)grow * 512 + coff + kp * 64 + slot * 8;
      float4 x0 = *(const float4*)xr;
      float4 x1 = *(const float4*)(xr + 4);
      float xs[8] = {x0.x, x0.y, x0.z, x0.w, x1.x, x1.y, x1.z, x1.w};
      union { half8 v; _Float16 h[8]; } H, L;
#pragma unroll
      for (int q = 0; q < 8; ++q) {
        _Float16 hv = (_Float16)xs[q];
        H.h[q] = hv;
        L.h[q] = (_Float16)(xs[q] - (float)hv);
      }
      int off = row * 64 + (slot ^ (row & 7)) * 8;
      if (side) { *(half8*)&Qhi[off] = H.v; *(half8*)&Qlo[off] = L.v; }
      else      { *(half8*)&Phi[off] = H.v; *(half8*)&Plo[off] = L.v; }
    }
    __syncthreads();
#pragma unroll
    for (int ch = 0; ch < 4; ++ch) {
      int s = ch * 2 + half;
      int arow = qi * 32 + rc, brow = qj * 32 + rc;
      int aoff = arow * 64 + (s ^ (arow & 7)) * 8;
      int boff = brow * 64 + (s ^ (brow & 7)) * 8;
      half8 Ah = *(const half8*)&Phi[aoff];
      half8 Al = *(const half8*)&Plo[aoff];
      half8 Bh = *(const half8*)&Qhi[boff];
      half8 Bl = *(const half8*)&Qlo[boff];
      accA = __builtin_amdgcn_mfma_f32_32x32x16_f16(Ah, Bh, accA, 0, 0, 0);
      accB = __builtin_amdgcn_mfma_f32_32x32x16_f16(Al, Bh, accB, 0, 0, 0);
      accB = __builtin_amdgcn_mfma_f32_32x32x16_f16(Ah, Bl, accB, 0, 0, 0);
    }
  }
  __syncthreads();
  bool offdiag = (tj > ti);
  int gj = tj * 64 + qj * 32 + rc;
  float sqj = nrmJ[qj * 32 + rc];
#pragma unroll
  for (int e = 0; e < 16; ++e) {
    int erow = (e & 3) + 8 * (e >> 2) + 4 * half;
    int gi = ti * 64 + qi * 32 + erow;
    float sqi = nrmI[qi * 32 + erow];
    float g = accA[e] + accB[e];
    float d = fmaxf(sqi - 2.f * g + sqj, 0.f);
    if (gi == gj) d = 0.f;
    unsigned db = __float_as_uint(d) & 0xFFFFFC00u;
    Dk[(size_t)(b * N_ + gi) * N_ + gj] = db | (unsigned)gj;
    if (offdiag)
      Tt[qj * 32 + rc][qi * 32 + erow] = db | (unsigned)gi;
  }
  if (offdiag) {
    __syncthreads();
#pragma unroll
    for (int it = 0; it < 4; ++it) {
      int u = tid + it * 256;
      int r  = u >> 4;
      int c4 = (u & 15) * 4;
      uint4 vv = *(const uint4*)&Tt[r][c4];
      *(uint4*)&Dk[(size_t)(b * N_ + tj * 64 + r) * N_ + ti * 64 + c4] = vv;
    }
  }
}

// ---------------------------------------------------------------------------
// DPP wave-min (verified round 10).
// ---------------------------------------------------------------------------
__device__ __forceinline__ unsigned wave_min_bcast(unsigned x) {
  unsigned t;
  t = (unsigned)__builtin_amdgcn_update_dpp(-1, (int)x, 0x111, 0xF, 0xF, false);
  x = min(x, t);
  t = (unsigned)__builtin_amdgcn_update_dpp(-1, (int)x, 0x112, 0xF, 0xF, false);
  x = min(x, t);
  t = (unsigned)__builtin_amdgcn_update_dpp(-1, (int)x, 0x114, 0xF, 0xF, false);
  x = min(x, t);
  t = (unsigned)__builtin_amdgcn_update_dpp(-1, (int)x, 0x118, 0xF, 0xF, false);
  x = min(x, t);
  t = (unsigned)__builtin_amdgcn_update_dpp(-1, (int)x, 0x142, 0xF, 0xF, false);
  x = min(x, t);
  t = (unsigned)__builtin_amdgcn_update_dpp(-1, (int)x, 0x143, 0xF, 0xF, false);
  x = min(x, t);
  return (unsigned)__builtin_amdgcn_readlane((int)x, 63);
}

__device__ __forceinline__ void topk_body(
    const unsigned* __restrict__ Dk, int* __restrict__ idx, int blk) {
  int w = threadIdx.x >> 6, lane = threadIdx.x & 63;
  int p = blk * 4 + w;
  const unsigned* row = Dk + (size_t)p * N_;
  unsigned key[16];
#pragma unroll
  for (int s = 0; s < 16; ++s) key[s] = row[lane + 64 * s];
  int base = p & ~(N_ - 1);
  for (int k = 0; k < KNN; ++k) {
    unsigned m = key[0];
#pragma unroll
    for (int s = 1; s < 16; ++s) m = min(m, key[s]);
    unsigned gm = wave_min_bcast(m);
    int j = (int)(gm & 1023u);
    if (lane == 0) idx[p * KNN + k] = base + j;
    if ((j & 63) == lane) key[j >> 6] = 0xFFFFFFFFu;
  }
}

// Pure topk (layer 1; transform1 lives in prelude).
__global__ __launch_bounds__(256) void topk_kernel(
    const unsigned* __restrict__ Dk, int* __restrict__ idx) {
  topk_body(Dk, idx, blockIdx.x);
}

// ---------------------------------------------------------------------------
// FUSED topk || MFMA transform (layers 2-4). Verified round 15.
// ---------------------------------------------------------------------------
template<int Cin, int Cmid>
__global__ __launch_bounds__(256) void topk_transform_kernel(
    const unsigned* __restrict__ Dk, int* __restrict__ idx,
    const float* __restrict__ X, int coff,
    const unsigned short* __restrict__ wdf, const unsigned short* __restrict__ wbf,
    const float* __restrict__ ba,
    unsigned short* __restrict__ u, unsigned short* __restrict__ v) {
  if (blockIdx.x < NP / 4) {
    topk_body(Dk, idx, blockIdx.x);
    return;
  }
  constexpr int KC = Cin / 16;
  constexpr int XB = NP / 128;
  int bx = blockIdx.x - NP / 4;
  int px = bx % XB, nt = bx / XB;
  int wv = threadIdx.x >> 6, lane = threadIdx.x & 63;
  int row = lane & 31, half = lane >> 5;
  int p0 = px * 128 + wv * 32;

  bf16x8 afr[KC];
  const float* xr = X + (size_t)(p0 + row) * 512 + coff + half * 8;
#pragma unroll
  for (int c = 0; c < KC; ++c) {
    float4 x0 = *(const float4*)(xr + c * 16);
    float4 x1 = *(const float4*)(xr + c * 16 + 4);
    union { bf16x8 vec; __hip_bfloat162 h[4]; } pk;
    pk.h[0] = __float22bfloat162_rn({x0.x, x0.y});
    pk.h[1] = __float22bfloat162_rn({x0.z, x0.w});
    pk.h[2] = __float22bfloat162_rn({x1.x, x1.y});
    pk.h[3] = __float22bfloat162_rn({x1.z, x1.w});
    afr[c] = pk.vec;
  }

  const unsigned short* wdl = wdf + ((size_t)nt * KC * 64 + lane) * 8;
  const unsigned short* wbl = wbf + ((size_t)nt * KC * 64 + lane) * 8;
  f32x16 au = {}, av = {};
#pragma unroll
  for (int c = 0; c < KC; ++c) {
    bf16x8 bd = *(const bf16x8*)(wdl + (size_t)c * 512);
    au = __builtin_amdgcn_mfma_f32_32x32x16_bf16(afr[c], bd, au, 0, 0, 0);
  }
#pragma unroll
  for (int c = 0; c < KC; ++c) {
    bf16x8 bv = *(const bf16x8*)(wbl + (size_t)c * 512);
    av = __builtin_amdgcn_mfma_f32_32x32x16_bf16(afr[c], bv, av, 0, 0, 0);
  }

  int m = nt * 32 + row;
  float bias = ba[m];
#pragma unroll
  for (int e = 0; e < 16; ++e) {
    int orow = (e & 3) + 8 * (e >> 2) + 4 * half;
    u[(size_t)(p0 + orow) * Cmid + m] = f2bf(au[e] + bias);
    v[(size_t)(p0 + orow) * Cmid + m] = f2bf(av[e]);
  }
}

// ---------------------------------------------------------------------------
// Edge MLP second GEMM + max-aggregate. Verified v1 main loop (do not
// perturb). v20: store epilogue additionally atomic-maxes each output into
// pooledU (monotone u32 map -> bit-exact float max, order-independent),
// eliminating the pool1 kernel and its 32MB xcat re-read.
// ---------------------------------------------------------------------------
template<int Cmid, int Cout, int CG>
__global__ __launch_bounds__(960, 3) void edge_mlp_kernel(
    const unsigned short* __restrict__ u, const unsigned short* __restrict__ v,
    const int* __restrict__ idx,
    const unsigned short* __restrict__ wbt, const float* __restrict__ bb,
    float* __restrict__ xcat, int coff, unsigned* __restrict__ pooledU) {
  constexpr int AP = Cmid + 8;
  constexpr int T  = CG / 32;
  constexpr int KC = Cmid / 16;
  constexpr int G  = Cout / CG;
  __shared__ __align__(16) unsigned short W_lds[CG * AP];
  __shared__ float qmax[120 * CG];
  int tid = threadIdx.x, w = tid >> 6, lane = tid & 63;
  int col = lane & 31, half = lane >> 5;

  int rg = blockIdx.x * 480 + w * 32 + col;
  int rgc = min(rg, NP * KNN - 1);
  int p  = rgc / 20;
  int j  = idx[rgc];
  const unsigned short* up = u + (size_t)p * Cmid + half * 8;
  const unsigned short* vp = v + (size_t)j * Cmid + half * 8;

  bf16x8 afr[KC];
#pragma unroll
  for (int c = 0; c < KC; ++c) {
    union { int4 i; __hip_bfloat162 h[4]; bf16x8 vec; } U, V, R;
    U.i = *(const int4*)(up + c * 16);
    V.i = *(const int4*)(vp + c * 16);
#pragma unroll
    for (int q = 0; q < 4; ++q) {
      float2 a = __bfloat1622float2(U.h[q]);
      float2 b = __bfloat1622float2(V.h[q]);
      R.h[q] = __float22bfloat162_rn({fmaxf(a.x + b.x, 0.f), fmaxf(a.y + b.y, 0.f)});
    }
    afr[c] = R.vec;
  }

  int brow = col * AP + half * 8;

  for (int g = 0; g < G; ++g) {
    __syncthreads();
    for (int i = tid; i < CG * (Cmid / 8); i += 960) {
      int rr = i / (Cmid / 8), q = i - rr * (Cmid / 8);
      *(int4*)&W_lds[rr * AP + q * 8] =
          *(const int4*)&wbt[(size_t)(g * CG + rr) * Cmid + q * 8];
    }
    __syncthreads();
    f32x16 acc[T] = {};
#pragma unroll
    for (int c = 0; c < KC; ++c) {
#pragma unroll
      for (int t = 0; t < T; ++t) {
        bf16x8 bf = *(const bf16x8*)&W_lds[brow + t * 32 * AP + c * 16];
        acc[t] = __builtin_amdgcn_mfma_f32_32x32x16_bf16(afr[c], bf, acc[t], 0, 0, 0);
      }
    }
#pragma unroll
    for (int t = 0; t < T; ++t) {
#pragma unroll
      for (int Q = 0; Q < 4; ++Q) {
        float m0 = fmaxf(fmaxf(acc[t][4 * Q], acc[t][4 * Q + 1]),
                         fmaxf(acc[t][4 * Q + 2], acc[t][4 * Q + 3]));
        qmax[(w * 8 + 2 * Q + half) * CG + t * 32 + col] = m0;
      }
    }
    __syncthreads();
    for (int i = tid; i < 24 * CG; i += 960) {
      int pl = i / CG, c2 = i - pl * CG;
      int pg = blockIdx.x * 24 + pl;
      if (pg < NP) {
        float mm = qmax[(pl * 5 + 0) * CG + c2];
#pragma unroll
        for (int qq = 1; qq < 5; ++qq) mm = fmaxf(mm, qmax[(pl * 5 + qq) * CG + c2]);
        float val = mm + bb[g * CG + c2];
        xcat[(size_t)pg * 512 + coff + g * CG + c2] = val;
        atomicMax(&pooledU[(pg >> 10) * 512 + coff + g * CG + c2], fmap(val));
      }
    }
  }
}

// ---------------------------------------------------------------------------
// FUSED pool + lin1: pooled maxes come from edge_mlp atomics (u32-mapped).
// ---------------------------------------------------------------------------
__global__ __launch_bounds__(256) void pool2lin1_kernel(
    const unsigned* __restrict__ pooledU, const float* __restrict__ W,
    const float* __restrict__ bias, float* __restrict__ h) {
  __shared__ float pl[512];
  int flat = blockIdx.x * 256 + threadIdx.x;
  int b = flat >> 10, m = flat & 1023;
  {
    int c0 = threadIdx.x * 2;
    pl[c0]     = funmap(pooledU[b * 512 + c0]);
    pl[c0 + 1] = funmap(pooledU[b * 512 + c0 + 1]);
  }
  __syncthreads();
  float s = 0.f;
  for (int c = 0; c < 512; ++c) s = fmaf(pl[c], W[(size_t)c * 1024 + m], s);
  h[flat] = s + bias[m];
}

// ---------------------------------------------------------------------------
// FUSED bn + lin2 (verified round 17).
// ---------------------------------------------------------------------------
__global__ __launch_bounds__(256) void bnlin2_kernel(
    const float* __restrict__ h, const float* __restrict__ gamma,
    const float* __restrict__ beta, const float* __restrict__ W,
    const float* __restrict__ bias, float* __restrict__ out) {
  __shared__ float h2l[1024];
  int b = blockIdx.x;
  for (int m = threadIdx.x; m < 1024; m += 256) {
    float s = 0.f;
    for (int bb = 0; bb < 16; ++bb) s += h[bb * 1024 + m];
    float mu = s * (1.f / 16.f);
    float vv = 0.f;
    for (int bb = 0; bb < 16; ++bb) {
      float d = h[bb * 1024 + m] - mu;
      vv = fmaf(d, d, vv);
    }
    vv *= (1.f / 16.f);
    float rstd = rsqrtf(vv + 1e-5f);
    float val = (h[b * 1024 + m] - mu) * (gamma[m] * rstd) + beta[m];
    h2l[m] = fmaxf(val, 0.f);
  }
  __syncthreads();
  if (threadIdx.x < 64) {
    int lane = threadIdx.x;
    float logit = 0.f;
    if (lane < 40) {
      logit = bias[lane];
      for (int c = 0; c < 1024; ++c)
        logit = fmaf(h2l[c], W[(size_t)c * 40 + lane], logit);
    }
    float mv = (lane < 40) ? logit : -__builtin_inff();
#pragma unroll
    for (int off = 32; off >= 1; off >>= 1) mv = fmaxf(mv, __shfl_xor(mv, off));
    float e = (lane < 40) ? expf(logit - mv) : 0.f;
#pragma unroll
    for (int off = 32; off >= 1; off >>= 1) e += __shfl_xor(e, off);
    float lse = mv + logf(e);
    if (lane < 40) out[b * 40 + lane] = logit - lse;
  }
}

// ---------------------------------------------------------------------------
extern "C" void kernel_launch(void* const* d_in, const int* in_sizes, int n_in,
                              void* d_out, int out_size, void* d_ws, size_t ws_size,
                              hipStream_t stream) {
  const float* pos    = (const float*)d_in[0];
  const float* W1a = (const float*)d_in[2];  const float* b1a = (const float*)d_in[3];
  const float* W1b = (const float*)d_in[4];  const float* b1b = (const float*)d_in[5];
  const float* W2a = (const float*)d_in[6];  const float* b2a = (const float*)d_in[7];
  const float* W2b = (const float*)d_in[8];  const float* b2b = (const float*)d_in[9];
  const float* W3a = (const float*)d_in[10]; const float* b3a = (const float*)d_in[11];
  const float* W3b = (const float*)d_in[12]; const float* b3b = (const float*)d_in[13];
  const float* W4a = (const float*)d_in[14]; const float* b4a = (const float*)d_in[15];
  const float* W4b = (const float*)d_in[16]; const float* b4b = (const float*)d_in[17];
  const float* lin1_w = (const float*)d_in[18]; const float* lin1_b = (const float*)d_in[19];
  const float* gamma  = (const float*)d_in[20]; const float* beta   = (const float*)d_in[21];
  const float* lin2_w = (const float*)d_in[22]; const float* lin2_b = (const float*)d_in[23];
  float* out = (float*)d_out;

  char* ws = (char*)d_ws;
  size_t off = 0;
  auto alloc = [&](size_t bytes) {
    void* p = ws + off; off += (bytes + 255) & ~(size_t)255; return p;
  };
  float*    xcat = (float*)alloc((size_t)NP * 512 * 4);   // 32 MB
  unsigned* Dk   = (unsigned*)alloc((size_t)NP * N_ * 4); // 64 MB
  unsigned short* u = (unsigned short*)alloc((size_t)NP * 256 * 2);  // 8.4 MB
  unsigned short* v = (unsigned short*)alloc((size_t)NP * 256 * 2);  // 8.4 MB
  int*      idx  = (int*)alloc((size_t)NP * KNN * 4);
  unsigned short* wbt1 = (unsigned short*)alloc(64 * 64 * 2);
  unsigned short* wbt2 = (unsigned short*)alloc(64 * 64 * 2);
  unsigned short* wbt3 = (unsigned short*)alloc(128 * 128 * 2);
  unsigned short* wbt4 = (unsigned short*)alloc(256 * 256 * 2);
  unsigned short* wd2 = (unsigned short*)alloc(64 * 64 * 2);
  unsigned short* wb2 = (unsigned short*)alloc(64 * 64 * 2);
  unsigned short* wd3 = (unsigned short*)alloc(64 * 128 * 2);
  unsigned short* wb3 = (unsigned short*)alloc(64 * 128 * 2);
  unsigned short* wd4 = (unsigned short*)alloc(128 * 256 * 2);
  unsigned short* wb4 = (unsigned short*)alloc(128 * 256 * 2);
  float* h      = (float*)alloc(16 * 1024 * 4);
  unsigned* pooledU = (unsigned*)alloc(16 * 512 * 4);

  const int EB = (NP * KNN + 479) / 480;   // 683 edge blocks
  const int TB = NP / 4;                   // 4096 topk blocks
  dim3 gt_grid(136, 1, 16);                // packed triangular (tj >= ti)

  // prelude: pairdist(C=3) || cvtall || transform1 || pooled-zero
  prelude_kernel<<<4097, 256, 0, stream>>>(
      pos, Dk,
      W1b, W2b, W3b, W4b, wbt1, wbt2, wbt3, wbt4,
      W2a, W3a, W4a, wd2, wb2, wd3, wb3, wd4, wb4,
      W1a, b1a, u, v, pooledU);
  // layer 1
  topk_kernel<<<TB, 256, 0, stream>>>(Dk, idx);
  edge_mlp_kernel<64, 64, 64><<<EB, 960, 0, stream>>>(u, v, idx, wbt1, b1b, xcat, 0, pooledU);
  // layer 2
  gramt_kernel<64><<<gt_grid, 256, 0, stream>>>(xcat, 0, Dk);
  topk_transform_kernel<64, 64><<<TB + (NP / 128) * 2, 256, 0, stream>>>(
      Dk, idx, xcat, 0, wd2, wb2, b2a, u, v);
  edge_mlp_kernel<64, 64, 64><<<EB, 960, 0, stream>>>(u, v, idx, wbt2, b2b, xcat, 64, pooledU);
  // layer 3
  gramt_kernel<64><<<gt_grid, 256, 0, stream>>>(xcat, 64, Dk);
  topk_transform_kernel<64, 128><<<TB + (NP / 128) * 4, 256, 0, stream>>>(
      Dk, idx, xcat, 64, wd3, wb3, b3a, u, v);
  edge_mlp_kernel<128, 128, 64><<<EB, 960, 0, stream>>>(u, v, idx, wbt3, b3b, xcat, 128, pooledU);
  // layer 4
  gramt_kernel<128><<<gt_grid, 256, 0, stream>>>(xcat, 128, Dk);
  topk_transform_kernel<128, 256><<<TB + (NP / 128) * 8, 256, 0, stream>>>(
      Dk, idx, xcat, 128, wd4, wb4, b4a, u, v);
  edge_mlp_kernel<256, 256, 64><<<EB, 960, 0, stream>>>(u, v, idx, wbt4, b4b, xcat, 256, pooledU);
  // head (pool via edge_mlp atomics -> lin1 -> bn+lin2)
  pool2lin1_kernel<<<64, 256, 0, stream>>>(pooledU, lin1_w, lin1_b, h);
  bnlin2_kernel<<<16, 256, 0, stream>>>(h, gamma, beta, lin2_w, lin2_b, out);
}

// Round 21
// 485.804 us; speedup vs baseline: 1.5355x; 1.5355x over previous
//
#include <hip/hip_runtime.h>
#include <hip/hip_bf16.h>
#include <hip/hip_fp16.h>

#define B_   16
#define N_   1024
#define KNN  20
#define NP   (B_ * N_)   // 16384

typedef short bf16x8 __attribute__((ext_vector_type(8)));
typedef _Float16 half8 __attribute__((ext_vector_type(8)));
typedef float f32x4  __attribute__((ext_vector_type(4)));
typedef float f32x16 __attribute__((ext_vector_type(16)));

__device__ __forceinline__ unsigned short f2bf(float f) {
  unsigned u = __float_as_uint(f);
  u += 0x7fffu + ((u >> 16) & 1u);   // RNE
  return (unsigned short)(u >> 16);
}

// ---------------------------------------------------------------------------
// FUSED PRELUDE: all input-only work in ONE dispatch.
//   blocks [0,2176):    pairdist (C=3, fp32 VALU) -- verified body
//   blocks [2176,3072): cvtall weight prep        -- verified body
//   blocks [3072,4096): transform1 (layer-1 u/v)  -- verified body
// ---------------------------------------------------------------------------
__global__ __launch_bounds__(256) void prelude_kernel(
    const float* __restrict__ pos, unsigned* __restrict__ Dk,
    const float* __restrict__ W0, const float* __restrict__ W1,
    const float* __restrict__ W2, const float* __restrict__ W3,
    unsigned short* __restrict__ o0, unsigned short* __restrict__ o1,
    unsigned short* __restrict__ o2, unsigned short* __restrict__ o3,
    const float* __restrict__ A2, const float* __restrict__ A3,
    const float* __restrict__ A4,
    unsigned short* __restrict__ d2, unsigned short* __restrict__ b2,
    unsigned short* __restrict__ d3, unsigned short* __restrict__ b3,
    unsigned short* __restrict__ d4, unsigned short* __restrict__ b4,
    const float* __restrict__ W1a, const float* __restrict__ b1a,
    unsigned short* __restrict__ u, unsigned short* __restrict__ v) {
  int blk = blockIdx.x;
  if (blk < 2176) {
    // ---------------- pairdist (C=3), verified body ----------------
    __shared__ __align__(16) char pd_smem[64 * 68 * 4];
    __shared__ float sqi_s[64], sqj_s[64];
    float (*Xi)[68] = (float(*)[68])pd_smem;
    float (*Xj)[68] = (float(*)[68])(pd_smem + 32 * 68 * 4);
    unsigned (*Tt)[68] = (unsigned(*)[68])pd_smem;
    const int LD = 3, coff = 0, C = 3;
    int lin = blk % 136, by = 0;
    int b = blk / 136;
    while (lin >= 16 - by) { lin -= 16 - by; ++by; }
    int bx = by + lin;
    int i0 = by * 64, j0 = bx * 64;
    int t  = threadIdx.x;
    int tx = t & 15, ty = t >> 4;
    int cx = t & 31, ry = t >> 5;
    float acc[4][4] = {};
    float sqacc = 0.f;
    for (int c0 = 0; c0 < C; c0 += 32) {
      int cc = min(32, C - c0);
      if (cx < cc) {
        for (int r = ry; r < 64; r += 8) {
          Xi[cx][r] = pos[(size_t)(b * N_ + i0 + r) * LD + coff + c0 + cx];
          Xj[cx][r] = pos[(size_t)(b * N_ + j0 + r) * LD + coff + c0 + cx];
        }
      }
      __syncthreads();
      if (t < 64) {
        for (int c = 0; c < cc; ++c) sqacc = fmaf(Xi[c][t], Xi[c][t], sqacc);
      } else if (t < 128) {
        int r = t - 64;
        for (int c = 0; c < cc; ++c) sqacc = fmaf(Xj[c][r], Xj[c][r], sqacc);
      }
      for (int c = 0; c < cc; ++c) {
        float4 a4 = *(const float4*)&Xi[c][ty * 4];
        float4 b4 = *(const float4*)&Xj[c][tx * 4];
        float a[4] = {a4.x, a4.y, a4.z, a4.w};
        float bb[4] = {b4.x, b4.y, b4.z, b4.w};
#pragma unroll
        for (int p = 0; p < 4; ++p)
#pragma unroll
          for (int q = 0; q < 4; ++q)
            acc[p][q] = fmaf(a[p], bb[q], acc[p][q]);
      }
      __syncthreads();
    }
    if (t < 64) sqi_s[t] = sqacc;
    else if (t < 128) sqj_s[t - 64] = sqacc;
    __syncthreads();
    float sqi[4], sqj[4];
#pragma unroll
    for (int p = 0; p < 4; ++p) sqi[p] = sqi_s[ty * 4 + p];
#pragma unroll
    for (int q = 0; q < 4; ++q) sqj[q] = sqj_s[tx * 4 + q];
    bool offdiag = (bx > by);
#pragma unroll
    for (int p = 0; p < 4; ++p) {
      uint4 st;
      unsigned* kk = (unsigned*)&st;
#pragma unroll
      for (int q = 0; q < 4; ++q) {
        float d = fmaxf((sqi[p] - 2.f * acc[p][q]) + sqj[q], 0.f);
        unsigned db = __float_as_uint(d) & 0xFFFFFC00u;
        kk[q] = db | (unsigned)(j0 + tx * 4 + q);
        if (offdiag)
          Tt[tx * 4 + q][ty * 4 + p] = db | (unsigned)(i0 + ty * 4 + p);
      }
      *(uint4*)&Dk[(size_t)(b * N_ + i0 + ty * 4 + p) * N_ + j0 + tx * 4] = st;
    }
    if (offdiag) {
      __syncthreads();
#pragma unroll
      for (int p = 0; p < 4; ++p) {
        *(uint4*)&Dk[(size_t)(b * N_ + j0 + ty * 4 + p) * N_ + i0 + tx * 4] =
            *(uint4*)&Tt[ty * 4 + p][tx * 4];
      }
    }
  } else if (blk < 3072) {
    // ---------------- cvtall, verified body (flattened grid) ----------------
    int t2 = blk - 2176;
    int gx = t2 & 15, gy = (t2 >> 4) & 7, z = t2 >> 7;
    if (z < 4) {
      __shared__ unsigned short tile[32][33];
      const float* W; unsigned short* out; int Cmid, Cout;
      if (z == 0)      { W = W0; out = o0; Cmid = 64;  Cout = 64;  }
      else if (z == 1) { W = W1; out = o1; Cmid = 64;  Cout = 64;  }
      else if (z == 2) { W = W2; out = o2; Cmid = 128; Cout = 128; }
      else             { W = W3; out = o3; Cmid = 256; Cout = 256; }
      int c0 = gx * 32, co0 = gy * 32;
      if (c0 >= Cmid || co0 >= Cout) return;
      int tx = threadIdx.x & 31, ty = threadIdx.x >> 5;   // 32 x 8
      for (int r = ty; r < 32; r += 8)
        tile[r][tx] = f2bf(W[(size_t)(c0 + r) * Cout + co0 + tx]);
      __syncthreads();
      for (int r = ty; r < 32; r += 8)
        out[(size_t)(co0 + r) * Cmid + c0 + tx] = tile[tx][r];
    } else {
      if (gy > 0) return;
      int zz = z - 4;
      const float* Wa; unsigned short *wd, *wb; int Cin, Cmid;
      if (zz == 0)      { Wa = A2; wd = d2; wb = b2; Cin = 64;  Cmid = 64;  }
      else if (zz == 1) { Wa = A3; wd = d3; wb = b3; Cin = 64;  Cmid = 128; }
      else              { Wa = A4; wd = d4; wb = b4; Cin = 128; Cmid = 256; }
      int KC = Cin / 16;
      int NC = (Cmid / 32) * KC * 64;
      int ci = gx * 256 + threadIdx.x;
      if (ci >= NC) return;
      int ntc = ci >> 6, lane = ci & 63;
      int nt = ntc / KC, c = ntc - nt * KC;
      int n  = nt * 32 + (lane & 31);
      int kb = c * 16 + (lane >> 5) * 8;
#pragma unroll
      for (int j = 0; j < 8; ++j) {
        float top = Wa[(size_t)(kb + j) * Cmid + n];
        float bot = Wa[(size_t)(Cin + kb + j) * Cmid + n];
        wd[(size_t)ci * 8 + j] = f2bf(top - bot);
        wb[(size_t)ci * 8 + j] = f2bf(bot);
      }
    }
  } else {
    // ---------------- transform1 (layer 1, Cin=3), verified body ----------
    __shared__ float xs[48];
    constexpr int Cin = 3, Cmid = 64;
    int w = threadIdx.x >> 6, lane = threadIdx.x & 63;
    int m  = lane;
    int p0 = (blk - 3072) * 16;
    for (int i = threadIdx.x; i < 16 * Cin; i += 256) {
      int pt = i / Cin, c = i - pt * Cin;
      xs[pt * Cin + c] = pos[(size_t)(p0 + pt) * 3 + c];
    }
    __syncthreads();
    const float* xw = xs + (w * 4) * Cin;
    float ua[4] = {0.f, 0.f, 0.f, 0.f}, va[4] = {0.f, 0.f, 0.f, 0.f};
    for (int c = 0; c < Cin; ++c) {
      float wt = W1a[(size_t)c * Cmid + m];
      float wb = W1a[(size_t)(Cin + c) * Cmid + m];
      float wd = wt - wb;
#pragma unroll
      for (int i = 0; i < 4; ++i) {
        float xv = xw[i * Cin + c];
        ua[i] = fmaf(xv, wd, ua[i]);
        va[i] = fmaf(xv, wb, va[i]);
      }
    }
    float bias = b1a[m];
#pragma unroll
    for (int i = 0; i < 4; ++i) {
      u[(size_t)(p0 + w * 4 + i) * Cmid + m] = f2bf(ua[i] + bias);
      v[(size_t)(p0 + w * 4 + i) * Cmid + m] = f2bf(va[i]);
    }
  }
}

// ---------------------------------------------------------------------------
// MFMA Gram pairdist (layers 2-4). Verified rounds 11/14/16 (dual acc).
// ---------------------------------------------------------------------------
template<int C>
__global__ __launch_bounds__(256) void gramt_kernel(
    const float* __restrict__ X, int coff, unsigned* __restrict__ Dk) {
  constexpr int KP = C / 64;
  constexpr int F4 = C / 4;       // float4 per row
  __shared__ __align__(16) char gt_smem[32768];   // Phi|Plo|Qhi|Qlo / Tt overlay
  unsigned short* Phi = (unsigned short*)gt_smem;        // 8KB each
  unsigned short* Plo = Phi + 4096;
  unsigned short* Qhi = Plo + 4096;
  unsigned short* Qlo = Qhi + 4096;
  unsigned (*Tt)[68] = (unsigned(*)[68])gt_smem;         // 17.4KB overlay
  __shared__ float nrmI[64], nrmJ[64];                   // outside overlay
  int tid = threadIdx.x, wv = tid >> 6, lane = tid & 63;
  int rc = lane & 31, half = lane >> 5;
  int lin = blockIdx.x, ti = 0;
  while (lin >= 16 - ti) { lin -= 16 - ti; ++ti; }
  int tj = ti + lin;
  int b  = blockIdx.z;
  int qi = wv >> 1, qj = wv & 1;

  {
    int pr  = tid >> 1, sub = tid & 1;      // pr: 0..127
    int side = pr >> 6, row = pr & 63;
    int grow = b * N_ + (side ? tj : ti) * 64 + row;
    const float4* xr = (const float4*)(X + (size_t)grow * 512 + coff);
    float s = 0.f;
#pragma unroll
    for (int k = sub; k < F4; k += 2) {
      float4 x4 = xr[k];
      s = fmaf(x4.x, x4.x, s); s = fmaf(x4.y, x4.y, s);
      s = fmaf(x4.z, x4.z, s); s = fmaf(x4.w, x4.w, s);
    }
    s += __shfl_xor(s, 1);
    if (sub == 0) { if (side) nrmJ[row] = s; else nrmI[row] = s; }
  }

  f32x16 accA = {}, accB = {};
#pragma unroll
  for (int kp = 0; kp < KP; ++kp) {
    if (kp) __syncthreads();
#pragma unroll
    for (int it = 0; it < 4; ++it) {
      int u = tid + it * 256;
      int side = u >> 9;
      int row  = (u >> 3) & 63;
      int slot = u & 7;
      int grow = b * N_ + (side ? tj : ti) * 64 + row;
      const float* xr = X + (size_t)grow * 512 + coff + kp * 64 + slot * 8;
      float4 x0 = *(const float4*)xr;
      float4 x1 = *(const float4*)(xr + 4);
      float xs[8] = {x0.x, x0.y, x0.z, x0.w, x1.x, x1.y, x1.z, x1.w};
      union { half8 v; _Float16 h[8]; } H, L;
#pragma unroll
      for (int q = 0; q < 8; ++q) {
        _Float16 hv = (_Float16)xs[q];
        H.h[q] = hv;
        L.h[q] = (_Float16)(xs[q] - (float)hv);
      }
      int off = row * 64 + (slot ^ (row & 7)) * 8;
      if (side) { *(half8*)&Qhi[off] = H.v; *(half8*)&Qlo[off] = L.v; }
      else      { *(half8*)&Phi[off] = H.v; *(half8*)&Plo[off] = L.v; }
    }
    __syncthreads();
#pragma unroll
    for (int ch = 0; ch < 4; ++ch) {
      int s = ch * 2 + half;
      int arow = qi * 32 + rc, brow = qj * 32 + rc;
      int aoff = arow * 64 + (s ^ (arow & 7)) * 8;
      int boff = brow * 64 + (s ^ (brow & 7)) * 8;
      half8 Ah = *(const half8*)&Phi[aoff];
      half8 Al = *(const half8*)&Plo[aoff];
      half8 Bh = *(const half8*)&Qhi[boff];
      half8 Bl = *(const half8*)&Qlo[boff];
      accA = __builtin_amdgcn_mfma_f32_32x32x16_f16(Ah, Bh, accA, 0, 0, 0);
      accB = __builtin_amdgcn_mfma_f32_32x32x16_f16(Al, Bh, accB, 0, 0, 0);
      accB = __builtin_amdgcn_mfma_f32_32x32x16_f16(Ah, Bl, accB, 0, 0, 0);
    }
  }
  __syncthreads();
  bool offdiag = (tj > ti);
  int gj = tj * 64 + qj * 32 + rc;
  float sqj = nrmJ[qj * 32 + rc];
#pragma unroll
  for (int e = 0; e < 16; ++e) {
    int erow = (e & 3) + 8 * (e >> 2) + 4 * half;
    int gi = ti * 64 + qi * 32 + erow;
    float sqi = nrmI[qi * 32 + erow];
    float g = accA[e] + accB[e];
    float d = fmaxf(sqi - 2.f * g + sqj, 0.f);
    if (gi == gj) d = 0.f;
    unsigned db = __float_as_uint(d) & 0xFFFFFC00u;
    Dk[(size_t)(b * N_ + gi) * N_ + gj] = db | (unsigned)gj;
    if (offdiag)
      Tt[qj * 32 + rc][qi * 32 + erow] = db | (unsigned)gi;
  }
  if (offdiag) {
    __syncthreads();
#pragma unroll
    for (int it = 0; it < 4; ++it) {
      int u = tid + it * 256;
      int r  = u >> 4;
      int c4 = (u & 15) * 4;
      uint4 vv = *(const uint4*)&Tt[r][c4];
      *(uint4*)&Dk[(size_t)(b * N_ + tj * 64 + r) * N_ + ti * 64 + c4] = vv;
    }
  }
}

// ---------------------------------------------------------------------------
// DPP wave-min (verified round 10).
// ---------------------------------------------------------------------------
__device__ __forceinline__ unsigned wave_min_bcast(unsigned x) {
  unsigned t;
  t = (unsigned)__builtin_amdgcn_update_dpp(-1, (int)x, 0x111, 0xF, 0xF, false);
  x = min(x, t);
  t = (unsigned)__builtin_amdgcn_update_dpp(-1, (int)x, 0x112, 0xF, 0xF, false);
  x = min(x, t);
  t = (unsigned)__builtin_amdgcn_update_dpp(-1, (int)x, 0x114, 0xF, 0xF, false);
  x = min(x, t);
  t = (unsigned)__builtin_amdgcn_update_dpp(-1, (int)x, 0x118, 0xF, 0xF, false);
  x = min(x, t);
  t = (unsigned)__builtin_amdgcn_update_dpp(-1, (int)x, 0x142, 0xF, 0xF, false);
  x = min(x, t);
  t = (unsigned)__builtin_amdgcn_update_dpp(-1, (int)x, 0x143, 0xF, 0xF, false);
  x = min(x, t);
  return (unsigned)__builtin_amdgcn_readlane((int)x, 63);
}

__device__ __forceinline__ void topk_body(
    const unsigned* __restrict__ Dk, int* __restrict__ idx, int blk) {
  int w = threadIdx.x >> 6, lane = threadIdx.x & 63;
  int p = blk * 4 + w;
  const unsigned* row = Dk + (size_t)p * N_;
  unsigned key[16];
#pragma unroll
  for (int s = 0; s < 16; ++s) key[s] = row[lane + 64 * s];
  int base = p & ~(N_ - 1);
  for (int k = 0; k < KNN; ++k) {
    unsigned m = key[0];
#pragma unroll
    for (int s = 1; s < 16; ++s) m = min(m, key[s]);
    unsigned gm = wave_min_bcast(m);
    int j = (int)(gm & 1023u);
    if (lane == 0) idx[p * KNN + k] = base + j;
    if ((j & 63) == lane) key[j >> 6] = 0xFFFFFFFFu;
  }
}

// Pure topk (layer 1; transform1 lives in prelude).
__global__ __launch_bounds__(256) void topk_kernel(
    const unsigned* __restrict__ Dk, int* __restrict__ idx) {
  topk_body(Dk, idx, blockIdx.x);
}

// ---------------------------------------------------------------------------
// FUSED topk || MFMA transform (layers 2-4). Verified round 15.
// ---------------------------------------------------------------------------
template<int Cin, int Cmid>
__global__ __launch_bounds__(256) void topk_transform_kernel(
    const unsigned* __restrict__ Dk, int* __restrict__ idx,
    const float* __restrict__ X, int coff,
    const unsigned short* __restrict__ wdf, const unsigned short* __restrict__ wbf,
    const float* __restrict__ ba,
    unsigned short* __restrict__ u, unsigned short* __restrict__ v) {
  if (blockIdx.x < NP / 4) {
    topk_body(Dk, idx, blockIdx.x);
    return;
  }
  constexpr int KC = Cin / 16;
  constexpr int XB = NP / 128;
  int bx = blockIdx.x - NP / 4;
  int px = bx % XB, nt = bx / XB;
  int wv = threadIdx.x >> 6, lane = threadIdx.x & 63;
  int row = lane & 31, half = lane >> 5;
  int p0 = px * 128 + wv * 32;

  bf16x8 afr[KC];
  const float* xr = X + (size_t)(p0 + row) * 512 + coff + half * 8;
#pragma unroll
  for (int c = 0; c < KC; ++c) {
    float4 x0 = *(const float4*)(xr + c * 16);
    float4 x1 = *(const float4*)(xr + c * 16 + 4);
    union { bf16x8 vec; __hip_bfloat162 h[4]; } pk;
    pk.h[0] = __float22bfloat162_rn({x0.x, x0.y});
    pk.h[1] = __float22bfloat162_rn({x0.z, x0.w});
    pk.h[2] = __float22bfloat162_rn({x1.x, x1.y});
    pk.h[3] = __float22bfloat162_rn({x1.z, x1.w});
    afr[c] = pk.vec;
  }

  const unsigned short* wdl = wdf + ((size_t)nt * KC * 64 + lane) * 8;
  const unsigned short* wbl = wbf + ((size_t)nt * KC * 64 + lane) * 8;
  f32x16 au = {}, av = {};
#pragma unroll
  for (int c = 0; c < KC; ++c) {
    bf16x8 bd = *(const bf16x8*)(wdl + (size_t)c * 512);
    au = __builtin_amdgcn_mfma_f32_32x32x16_bf16(afr[c], bd, au, 0, 0, 0);
  }
#pragma unroll
  for (int c = 0; c < KC; ++c) {
    bf16x8 bv = *(const bf16x8*)(wbl + (size_t)c * 512);
    av = __builtin_amdgcn_mfma_f32_32x32x16_bf16(afr[c], bv, av, 0, 0, 0);
  }

  int m = nt * 32 + row;
  float bias = ba[m];
#pragma unroll
  for (int e = 0; e < 16; ++e) {
    int orow = (e & 3) + 8 * (e >> 2) + 4 * half;
    u[(size_t)(p0 + orow) * Cmid + m] = f2bf(au[e] + bias);
    v[(size_t)(p0 + orow) * Cmid + m] = f2bf(av[e]);
  }
}

// ---------------------------------------------------------------------------
// Edge MLP second GEMM + max-aggregate. Verified v1 structure. Do not perturb.
// ---------------------------------------------------------------------------
template<int Cmid, int Cout, int CG>
__global__ __launch_bounds__(960, 3) void edge_mlp_kernel(
    const unsigned short* __restrict__ u, const unsigned short* __restrict__ v,
    const int* __restrict__ idx,
    const unsigned short* __restrict__ wbt, const float* __restrict__ bb,
    float* __restrict__ xcat, int coff) {
  constexpr int AP = Cmid + 8;
  constexpr int T  = CG / 32;
  constexpr int KC = Cmid / 16;
  constexpr int G  = Cout / CG;
  __shared__ __align__(16) unsigned short W_lds[CG * AP];
  __shared__ float qmax[120 * CG];
  int tid = threadIdx.x, w = tid >> 6, lane = tid & 63;
  int col = lane & 31, half = lane >> 5;

  int rg = blockIdx.x * 480 + w * 32 + col;
  int rgc = min(rg, NP * KNN - 1);
  int p  = rgc / 20;
  int j  = idx[rgc];
  const unsigned short* up = u + (size_t)p * Cmid + half * 8;
  const unsigned short* vp = v + (size_t)j * Cmid + half * 8;

  bf16x8 afr[KC];
#pragma unroll
  for (int c = 0; c < KC; ++c) {
    union { int4 i; __hip_bfloat162 h[4]; bf16x8 vec; } U, V, R;
    U.i = *(const int4*)(up + c * 16);
    V.i = *(const int4*)(vp + c * 16);
#pragma unroll
    for (int q = 0; q < 4; ++q) {
      float2 a = __bfloat1622float2(U.h[q]);
      float2 b = __bfloat1622float2(V.h[q]);
      R.h[q] = __float22bfloat162_rn({fmaxf(a.x + b.x, 0.f), fmaxf(a.y + b.y, 0.f)});
    }
    afr[c] = R.vec;
  }

  int brow = col * AP + half * 8;

  for (int g = 0; g < G; ++g) {
    __syncthreads();
    for (int i = tid; i < CG * (Cmid / 8); i += 960) {
      int rr = i / (Cmid / 8), q = i - rr * (Cmid / 8);
      *(int4*)&W_lds[rr * AP + q * 8] =
          *(const int4*)&wbt[(size_t)(g * CG + rr) * Cmid + q * 8];
    }
    __syncthreads();
    f32x16 acc[T] = {};
#pragma unroll
    for (int c = 0; c < KC; ++c) {
#pragma unroll
      for (int t = 0; t < T; ++t) {
        bf16x8 bf = *(const bf16x8*)&W_lds[brow + t * 32 * AP + c * 16];
        acc[t] = __builtin_amdgcn_mfma_f32_32x32x16_bf16(afr[c], bf, acc[t], 0, 0, 0);
      }
    }
#pragma unroll
    for (int t = 0; t < T; ++t) {
#pragma unroll
      for (int Q = 0; Q < 4; ++Q) {
        float m0 = fmaxf(fmaxf(acc[t][4 * Q], acc[t][4 * Q + 1]),
                         fmaxf(acc[t][4 * Q + 2], acc[t][4 * Q + 3]));
        qmax[(w * 8 + 2 * Q + half) * CG + t * 32 + col] = m0;
      }
    }
    __syncthreads();
    for (int i = tid; i < 24 * CG; i += 960) {
      int pl = i / CG, c2 = i - pl * CG;
      int pg = blockIdx.x * 24 + pl;
      if (pg < NP) {
        float mm = qmax[(pl * 5 + 0) * CG + c2];
#pragma unroll
        for (int qq = 1; qq < 5; ++qq) mm = fmaxf(mm, qmax[(pl * 5 + qq) * CG + c2]);
        xcat[(size_t)pg * 512 + coff + g * CG + c2] = mm + bb[g * CG + c2];
      }
    }
  }
}

// ---------------------------------------------------------------------------
// Global max pool stage 1 (verified); stage 2 fused into lin1 below.
// ---------------------------------------------------------------------------
__global__ __launch_bounds__(256) void pool1_kernel(const float* __restrict__ xcat,
                                                    float* __restrict__ part) {
  int b = blockIdx.x, g = blockIdx.y, t = threadIdx.x;
  const float* base = xcat + ((size_t)b * N_ + g * 128) * 512 + t * 2;
  float mx = -__builtin_inff(), my = -__builtin_inff();
#pragma unroll 4
  for (int r = 0; r < 128; ++r) {
    float2 vv = *(const float2*)(base + (size_t)r * 512);
    mx = fmaxf(mx, vv.x);
    my = fmaxf(my, vv.y);
  }
  *(float2*)&part[((size_t)b * 8 + g) * 512 + t * 2] = make_float2(mx, my);
}

// ---------------------------------------------------------------------------
// FUSED pool2 + lin1 (verified round 17).
// ---------------------------------------------------------------------------
__global__ __launch_bounds__(256) void pool2lin1_kernel(
    const float* __restrict__ part, const float* __restrict__ W,
    const float* __restrict__ bias, float* __restrict__ h) {
  __shared__ float pl[512];
  int flat = blockIdx.x * 256 + threadIdx.x;
  int b = flat >> 10, m = flat & 1023;
  {
    int c0 = threadIdx.x * 2;
    float2 mx = *(const float2*)&part[((size_t)b * 8 + 0) * 512 + c0];
#pragma unroll
    for (int g = 1; g < 8; ++g) {
      float2 vv = *(const float2*)&part[((size_t)b * 8 + g) * 512 + c0];
      mx.x = fmaxf(mx.x, vv.x);
      mx.y = fmaxf(mx.y, vv.y);
    }
    pl[c0] = mx.x;
    pl[c0 + 1] = mx.y;
  }
  __syncthreads();
  float s = 0.f;
  for (int c = 0; c < 512; ++c) s = fmaf(pl[c], W[(size_t)c * 1024 + m], s);
  h[flat] = s + bias[m];
}

// ---------------------------------------------------------------------------
// FUSED bn + lin2 (verified round 17).
// ---------------------------------------------------------------------------
__global__ __launch_bounds__(256) void bnlin2_kernel(
    const float* __restrict__ h, const float* __restrict__ gamma,
    const float* __restrict__ beta, const float* __restrict__ W,
    const float* __restrict__ bias, float* __restrict__ out) {
  __shared__ float h2l[1024];
  int b = blockIdx.x;
  for (int m = threadIdx.x; m < 1024; m += 256) {
    float s = 0.f;
    for (int bb = 0; bb < 16; ++bb) s += h[bb * 1024 + m];
    float mu = s * (1.f / 16.f);
    float vv = 0.f;
    for (int bb = 0; bb < 16; ++bb) {
      float d = h[bb * 1024 + m] - mu;
      vv = fmaf(d, d, vv);
    }
    vv *= (1.f / 16.f);
    float rstd = rsqrtf(vv + 1e-5f);
    float val = (h[b * 1024 + m] - mu) * (gamma[m] * rstd) + beta[m];
    h2l[m] = fmaxf(val, 0.f);
  }
  __syncthreads();
  if (threadIdx.x < 64) {
    int lane = threadIdx.x;
    float logit = 0.f;
    if (lane < 40) {
      logit = bias[lane];
      for (int c = 0; c < 1024; ++c)
        logit = fmaf(h2l[c], W[(size_t)c * 40 + lane], logit);
    }
    float mv = (lane < 40) ? logit : -__builtin_inff();
#pragma unroll
    for (int off = 32; off >= 1; off >>= 1) mv = fmaxf(mv, __shfl_xor(mv, off));
    float e = (lane < 40) ? expf(logit - mv) : 0.f;
#pragma unroll
    for (int off = 32; off >= 1; off >>= 1) e += __shfl_xor(e, off);
    float lse = mv + logf(e);
    if (lane < 40) out[b * 40 + lane] = logit - lse;
  }
}

// ---------------------------------------------------------------------------
extern "C" void kernel_launch(void* const* d_in, const int* in_sizes, int n_in,
                              void* d_out, int out_size, void* d_ws, size_t ws_size,
                              hipStream_t stream) {
  const float* pos    = (const float*)d_in[0];
  const float* W1a = (const float*)d_in[2];  const float* b1a = (const float*)d_in[3];
  const float* W1b = (const float*)d_in[4];  const float* b1b = (const float*)d_in[5];
  const float* W2a = (const float*)d_in[6];  const float* b2a = (const float*)d_in[7];
  const float* W2b = (const float*)d_in[8];  const float* b2b = (const float*)d_in[9];
  const float* W3a = (const float*)d_in[10]; const float* b3a = (const float*)d_in[11];
  const float* W3b = (const float*)d_in[12]; const float* b3b = (const float*)d_in[13];
  const float* W4a = (const float*)d_in[14]; const float* b4a = (const float*)d_in[15];
  const float* W4b = (const float*)d_in[16]; const float* b4b = (const float*)d_in[17];
  const float* lin1_w = (const float*)d_in[18]; const float* lin1_b = (const float*)d_in[19];
  const float* gamma  = (const float*)d_in[20]; const float* beta   = (const float*)d_in[21];
  const float* lin2_w = (const float*)d_in[22]; const float* lin2_b = (const float*)d_in[23];
  float* out = (float*)d_out;

  char* ws = (char*)d_ws;
  size_t off = 0;
  auto alloc = [&](size_t bytes) {
    void* p = ws + off; off += (bytes + 255) & ~(size_t)255; return p;
  };
  float*    xcat = (float*)alloc((size_t)NP * 512 * 4);   // 32 MB
  unsigned* Dk   = (unsigned*)alloc((size_t)NP * N_ * 4); // 64 MB
  unsigned short* u = (unsigned short*)alloc((size_t)NP * 256 * 2);  // 8.4 MB
  unsigned short* v = (unsigned short*)alloc((size_t)NP * 256 * 2);  // 8.4 MB
  int*      idx  = (int*)alloc((size_t)NP * KNN * 4);
  unsigned short* wbt1 = (unsigned short*)alloc(64 * 64 * 2);
  unsigned short* wbt2 = (unsigned short*)alloc(64 * 64 * 2);
  unsigned short* wbt3 = (unsigned short*)alloc(128 * 128 * 2);
  unsigned short* wbt4 = (unsigned short*)alloc(256 * 256 * 2);
  unsigned short* wd2 = (unsigned short*)alloc(64 * 64 * 2);
  unsigned short* wb2 = (unsigned short*)alloc(64 * 64 * 2);
  unsigned short* wd3 = (unsigned short*)alloc(64 * 128 * 2);
  unsigned short* wb3 = (unsigned short*)alloc(64 * 128 * 2);
  unsigned short* wd4 = (unsigned short*)alloc(128 * 256 * 2);
  unsigned short* wb4 = (unsigned short*)alloc(128 * 256 * 2);
  float* h      = (float*)alloc(16 * 1024 * 4);
  float* part   = (float*)alloc(16 * 8 * 512 * 4);

  const int EB = (NP * KNN + 479) / 480;   // 683 edge blocks
  const int TB = NP / 4;                   // 4096 topk blocks
  dim3 gt_grid(136, 1, 16);                // packed triangular (tj >= ti)

  // prelude: pairdist(C=3) || cvtall || transform1 in ONE dispatch
  prelude_kernel<<<4096, 256, 0, stream>>>(
      pos, Dk,
      W1b, W2b, W3b, W4b, wbt1, wbt2, wbt3, wbt4,
      W2a, W3a, W4a, wd2, wb2, wd3, wb3, wd4, wb4,
      W1a, b1a, u, v);
  // layer 1
  topk_kernel<<<TB, 256, 0, stream>>>(Dk, idx);
  edge_mlp_kernel<64, 64, 64><<<EB, 960, 0, stream>>>(u, v, idx, wbt1, b1b, xcat, 0);
  // layer 2
  gramt_kernel<64><<<gt_grid, 256, 0, stream>>>(xcat, 0, Dk);
  topk_transform_kernel<64, 64><<<TB + (NP / 128) * 2, 256, 0, stream>>>(
      Dk, idx, xcat, 0, wd2, wb2, b2a, u, v);
  edge_mlp_kernel<64, 64, 64><<<EB, 960, 0, stream>>>(u, v, idx, wbt2, b2b, xcat, 64);
  // layer 3
  gramt_kernel<64><<<gt_grid, 256, 0, stream>>>(xcat, 64, Dk);
  topk_transform_kernel<64, 128><<<TB + (NP / 128) * 4, 256, 0, stream>>>(
      Dk, idx, xcat, 64, wd3, wb3, b3a, u, v);
  edge_mlp_kernel<128, 128, 64><<<EB, 960, 0, stream>>>(u, v, idx, wbt3, b3b, xcat, 128);
  // layer 4
  gramt_kernel<128><<<gt_grid, 256, 0, stream>>>(xcat, 128, Dk);
  topk_transform_kernel<128, 256><<<TB + (NP / 128) * 8, 256, 0, stream>>>(
      Dk, idx, xcat, 128, wd4, wb4, b4a, u, v);
  edge_mlp_kernel<256, 256, 64><<<EB, 960, 0, stream>>>(u, v, idx, wbt4, b4b, xcat, 256);
  // head (pool1 -> pool2+lin1 -> bn+lin2)
  pool1_kernel<<<dim3(16, 8), 256, 0, stream>>>(xcat, part);
  pool2lin1_kernel<<<64, 256, 0, stream>>>(part, lin1_w, lin1_b, h);
  bnlin2_kernel<<<16, 256, 0, stream>>>(h, gamma, beta, lin2_w, lin2_b, out);
}

// Round 22
// 482.964 us; speedup vs baseline: 1.5445x; 1.0059x over previous
//
#include <hip/hip_runtime.h>
#include <hip/hip_bf16.h>
#include <hip/hip_fp16.h>

#define B_   16
#define N_   1024
#define KNN  20
#define NP   (B_ * N_)   // 16384

typedef short bf16x8 __attribute__((ext_vector_type(8)));
typedef _Float16 half8 __attribute__((ext_vector_type(8)));
typedef float f32x4  __attribute__((ext_vector_type(4)));
typedef float f32x16 __attribute__((ext_vector_type(16)));

__device__ __forceinline__ unsigned short f2bf(float f) {
  unsigned u = __float_as_uint(f);
  u += 0x7fffu + ((u >> 16) & 1u);   // RNE
  return (unsigned short)(u >> 16);
}

// Bijective XCD-aware block swizzle (T1, m204 formula): hardware dispatches
// blocks round-robin across 8 XCDs; this remap gives each XCD a CONTIGUOUS
// chunk of the grid so blocks sharing a cloud's v-rows land on one L2.
__device__ __forceinline__ int xcd_swz(int orig, int nwg) {
  int q = nwg >> 3, r = nwg & 7;
  int xcd = orig & 7, i = orig >> 3;
  return (xcd < r ? xcd * (q + 1) : r * (q + 1) + (xcd - r) * q) + i;
}

// ---------------------------------------------------------------------------
// FUSED PRELUDE: all input-only work in ONE dispatch.
//   blocks [0,2176):    pairdist (C=3, fp32 VALU) -- verified body
//   blocks [2176,3072): cvtall weight prep        -- verified body
//   blocks [3072,4096): transform1 (layer-1 u/v)  -- verified body
// ---------------------------------------------------------------------------
__global__ __launch_bounds__(256) void prelude_kernel(
    const float* __restrict__ pos, unsigned* __restrict__ Dk,
    const float* __restrict__ W0, const float* __restrict__ W1,
    const float* __restrict__ W2, const float* __restrict__ W3,
    unsigned short* __restrict__ o0, unsigned short* __restrict__ o1,
    unsigned short* __restrict__ o2, unsigned short* __restrict__ o3,
    const float* __restrict__ A2, const float* __restrict__ A3,
    const float* __restrict__ A4,
    unsigned short* __restrict__ d2, unsigned short* __restrict__ b2,
    unsigned short* __restrict__ d3, unsigned short* __restrict__ b3,
    unsigned short* __restrict__ d4, unsigned short* __restrict__ b4,
    const float* __restrict__ W1a, const float* __restrict__ b1a,
    unsigned short* __restrict__ u, unsigned short* __restrict__ v) {
  int blk = blockIdx.x;
  if (blk < 2176) {
    // ---------------- pairdist (C=3), verified body ----------------
    __shared__ __align__(16) char pd_smem[64 * 68 * 4];
    __shared__ float sqi_s[64], sqj_s[64];
    float (*Xi)[68] = (float(*)[68])pd_smem;
    float (*Xj)[68] = (float(*)[68])(pd_smem + 32 * 68 * 4);
    unsigned (*Tt)[68] = (unsigned(*)[68])pd_smem;
    const int LD = 3, coff = 0, C = 3;
    int lin = blk % 136, by = 0;
    int b = blk / 136;
    while (lin >= 16 - by) { lin -= 16 - by; ++by; }
    int bx = by + lin;
    int i0 = by * 64, j0 = bx * 64;
    int t  = threadIdx.x;
    int tx = t & 15, ty = t >> 4;
    int cx = t & 31, ry = t >> 5;
    float acc[4][4] = {};
    float sqacc = 0.f;
    for (int c0 = 0; c0 < C; c0 += 32) {
      int cc = min(32, C - c0);
      if (cx < cc) {
        for (int r = ry; r < 64; r += 8) {
          Xi[cx][r] = pos[(size_t)(b * N_ + i0 + r) * LD + coff + c0 + cx];
          Xj[cx][r] = pos[(size_t)(b * N_ + j0 + r) * LD + coff + c0 + cx];
        }
      }
      __syncthreads();
      if (t < 64) {
        for (int c = 0; c < cc; ++c) sqacc = fmaf(Xi[c][t], Xi[c][t], sqacc);
      } else if (t < 128) {
        int r = t - 64;
        for (int c = 0; c < cc; ++c) sqacc = fmaf(Xj[c][r], Xj[c][r], sqacc);
      }
      for (int c = 0; c < cc; ++c) {
        float4 a4 = *(const float4*)&Xi[c][ty * 4];
        float4 b4 = *(const float4*)&Xj[c][tx * 4];
        float a[4] = {a4.x, a4.y, a4.z, a4.w};
        float bb[4] = {b4.x, b4.y, b4.z, b4.w};
#pragma unroll
        for (int p = 0; p < 4; ++p)
#pragma unroll
          for (int q = 0; q < 4; ++q)
            acc[p][q] = fmaf(a[p], bb[q], acc[p][q]);
      }
      __syncthreads();
    }
    if (t < 64) sqi_s[t] = sqacc;
    else if (t < 128) sqj_s[t - 64] = sqacc;
    __syncthreads();
    float sqi[4], sqj[4];
#pragma unroll
    for (int p = 0; p < 4; ++p) sqi[p] = sqi_s[ty * 4 + p];
#pragma unroll
    for (int q = 0; q < 4; ++q) sqj[q] = sqj_s[tx * 4 + q];
    bool offdiag = (bx > by);
#pragma unroll
    for (int p = 0; p < 4; ++p) {
      uint4 st;
      unsigned* kk = (unsigned*)&st;
#pragma unroll
      for (int q = 0; q < 4; ++q) {
        float d = fmaxf((sqi[p] - 2.f * acc[p][q]) + sqj[q], 0.f);
        unsigned db = __float_as_uint(d) & 0xFFFFFC00u;
        kk[q] = db | (unsigned)(j0 + tx * 4 + q);
        if (offdiag)
          Tt[tx * 4 + q][ty * 4 + p] = db | (unsigned)(i0 + ty * 4 + p);
      }
      *(uint4*)&Dk[(size_t)(b * N_ + i0 + ty * 4 + p) * N_ + j0 + tx * 4] = st;
    }
    if (offdiag) {
      __syncthreads();
#pragma unroll
      for (int p = 0; p < 4; ++p) {
        *(uint4*)&Dk[(size_t)(b * N_ + j0 + ty * 4 + p) * N_ + i0 + tx * 4] =
            *(uint4*)&Tt[ty * 4 + p][tx * 4];
      }
    }
  } else if (blk < 3072) {
    // ---------------- cvtall, verified body (flattened grid) ----------------
    int t2 = blk - 2176;
    int gx = t2 & 15, gy = (t2 >> 4) & 7, z = t2 >> 7;
    if (z < 4) {
      __shared__ unsigned short tile[32][33];
      const float* W; unsigned short* out; int Cmid, Cout;
      if (z == 0)      { W = W0; out = o0; Cmid = 64;  Cout = 64;  }
      else if (z == 1) { W = W1; out = o1; Cmid = 64;  Cout = 64;  }
      else if (z == 2) { W = W2; out = o2; Cmid = 128; Cout = 128; }
      else             { W = W3; out = o3; Cmid = 256; Cout = 256; }
      int c0 = gx * 32, co0 = gy * 32;
      if (c0 >= Cmid || co0 >= Cout) return;
      int tx = threadIdx.x & 31, ty = threadIdx.x >> 5;   // 32 x 8
      for (int r = ty; r < 32; r += 8)
        tile[r][tx] = f2bf(W[(size_t)(c0 + r) * Cout + co0 + tx]);
      __syncthreads();
      for (int r = ty; r < 32; r += 8)
        out[(size_t)(co0 + r) * Cmid + c0 + tx] = tile[tx][r];
    } else {
      if (gy > 0) return;
      int zz = z - 4;
      const float* Wa; unsigned short *wd, *wb; int Cin, Cmid;
      if (zz == 0)      { Wa = A2; wd = d2; wb = b2; Cin = 64;  Cmid = 64;  }
      else if (zz == 1) { Wa = A3; wd = d3; wb = b3; Cin = 64;  Cmid = 128; }
      else              { Wa = A4; wd = d4; wb = b4; Cin = 128; Cmid = 256; }
      int KC = Cin / 16;
      int NC = (Cmid / 32) * KC * 64;
      int ci = gx * 256 + threadIdx.x;
      if (ci >= NC) return;
      int ntc = ci >> 6, lane = ci & 63;
      int nt = ntc / KC, c = ntc - nt * KC;
      int n  = nt * 32 + (lane & 31);
      int kb = c * 16 + (lane >> 5) * 8;
#pragma unroll
      for (int j = 0; j < 8; ++j) {
        float top = Wa[(size_t)(kb + j) * Cmid + n];
        float bot = Wa[(size_t)(Cin + kb + j) * Cmid + n];
        wd[(size_t)ci * 8 + j] = f2bf(top - bot);
        wb[(size_t)ci * 8 + j] = f2bf(bot);
      }
    }
  } else {
    // ---------------- transform1 (layer 1, Cin=3), verified body ----------
    __shared__ float xs[48];
    constexpr int Cin = 3, Cmid = 64;
    int w = threadIdx.x >> 6, lane = threadIdx.x & 63;
    int m  = lane;
    int p0 = (blk - 3072) * 16;
    for (int i = threadIdx.x; i < 16 * Cin; i += 256) {
      int pt = i / Cin, c = i - pt * Cin;
      xs[pt * Cin + c] = pos[(size_t)(p0 + pt) * 3 + c];
    }
    __syncthreads();
    const float* xw = xs + (w * 4) * Cin;
    float ua[4] = {0.f, 0.f, 0.f, 0.f}, va[4] = {0.f, 0.f, 0.f, 0.f};
    for (int c = 0; c < Cin; ++c) {
      float wt = W1a[(size_t)c * Cmid + m];
      float wb = W1a[(size_t)(Cin + c) * Cmid + m];
      float wd = wt - wb;
#pragma unroll
      for (int i = 0; i < 4; ++i) {
        float xv = xw[i * Cin + c];
        ua[i] = fmaf(xv, wd, ua[i]);
        va[i] = fmaf(xv, wb, va[i]);
      }
    }
    float bias = b1a[m];
#pragma unroll
    for (int i = 0; i < 4; ++i) {
      u[(size_t)(p0 + w * 4 + i) * Cmid + m] = f2bf(ua[i] + bias);
      v[(size_t)(p0 + w * 4 + i) * Cmid + m] = f2bf(va[i]);
    }
  }
}

// ---------------------------------------------------------------------------
// MFMA Gram pairdist (layers 2-4). Verified rounds 11/14/16 (dual acc).
// ---------------------------------------------------------------------------
template<int C>
__global__ __launch_bounds__(256) void gramt_kernel(
    const float* __restrict__ X, int coff, unsigned* __restrict__ Dk) {
  constexpr int KP = C / 64;
  constexpr int F4 = C / 4;       // float4 per row
  __shared__ __align__(16) char gt_smem[32768];   // Phi|Plo|Qhi|Qlo / Tt overlay
  unsigned short* Phi = (unsigned short*)gt_smem;        // 8KB each
  unsigned short* Plo = Phi + 4096;
  unsigned short* Qhi = Plo + 4096;
  unsigned short* Qlo = Qhi + 4096;
  unsigned (*Tt)[68] = (unsigned(*)[68])gt_smem;         // 17.4KB overlay
  __shared__ float nrmI[64], nrmJ[64];                   // outside overlay
  int tid = threadIdx.x, wv = tid >> 6, lane = tid & 63;
  int rc = lane & 31, half = lane >> 5;
  int lin = blockIdx.x, ti = 0;
  while (lin >= 16 - ti) { lin -= 16 - ti; ++ti; }
  int tj = ti + lin;
  int b  = blockIdx.z;
  int qi = wv >> 1, qj = wv & 1;

  {
    int pr  = tid >> 1, sub = tid & 1;      // pr: 0..127
    int side = pr >> 6, row = pr & 63;
    int grow = b * N_ + (side ? tj : ti) * 64 + row;
    const float4* xr = (const float4*)(X + (size_t)grow * 512 + coff);
    float s = 0.f;
#pragma unroll
    for (int k = sub; k < F4; k += 2) {
      float4 x4 = xr[k];
      s = fmaf(x4.x, x4.x, s); s = fmaf(x4.y, x4.y, s);
      s = fmaf(x4.z, x4.z, s); s = fmaf(x4.w, x4.w, s);
    }
    s += __shfl_xor(s, 1);
    if (sub == 0) { if (side) nrmJ[row] = s; else nrmI[row] = s; }
  }

  f32x16 accA = {}, accB = {};
#pragma unroll
  for (int kp = 0; kp < KP; ++kp) {
    if (kp) __syncthreads();
#pragma unroll
    for (int it = 0; it < 4; ++it) {
      int u = tid + it * 256;
      int side = u >> 9;
      int row  = (u >> 3) & 63;
      int slot = u & 7;
      int grow = b * N_ + (side ? tj : ti) * 64 + row;
      const float* xr = X + (size_t)grow * 512 + coff + kp * 64 + slot * 8;
      float4 x0 = *(const float4*)xr;
      float4 x1 = *(const float4*)(xr + 4);
      float xs[8] = {x0.x, x0.y, x0.z, x0.w, x1.x, x1.y, x1.z, x1.w};
      union { half8 v; _Float16 h[8]; } H, L;
#pragma unroll
      for (int q = 0; q < 8; ++q) {
        _Float16 hv = (_Float16)xs[q];
        H.h[q] = hv;
        L.h[q] = (_Float16)(xs[q] - (float)hv);
      }
      int off = row * 64 + (slot ^ (row & 7)) * 8;
      if (side) { *(half8*)&Qhi[off] = H.v; *(half8*)&Qlo[off] = L.v; }
      else      { *(half8*)&Phi[off] = H.v; *(half8*)&Plo[off] = L.v; }
    }
    __syncthreads();
#pragma unroll
    for (int ch = 0; ch < 4; ++ch) {
      int s = ch * 2 + half;
      int arow = qi * 32 + rc, brow = qj * 32 + rc;
      int aoff = arow * 64 + (s ^ (arow & 7)) * 8;
      int boff = brow * 64 + (s ^ (brow & 7)) * 8;
      half8 Ah = *(const half8*)&Phi[aoff];
      half8 Al = *(const half8*)&Plo[aoff];
      half8 Bh = *(const half8*)&Qhi[boff];
      half8 Bl = *(const half8*)&Qlo[boff];
      accA = __builtin_amdgcn_mfma_f32_32x32x16_f16(Ah, Bh, accA, 0, 0, 0);
      accB = __builtin_amdgcn_mfma_f32_32x32x16_f16(Al, Bh, accB, 0, 0, 0);
      accB = __builtin_amdgcn_mfma_f32_32x32x16_f16(Ah, Bl, accB, 0, 0, 0);
    }
  }
  __syncthreads();
  bool offdiag = (tj > ti);
  int gj = tj * 64 + qj * 32 + rc;
  float sqj = nrmJ[qj * 32 + rc];
#pragma unroll
  for (int e = 0; e < 16; ++e) {
    int erow = (e & 3) + 8 * (e >> 2) + 4 * half;
    int gi = ti * 64 + qi * 32 + erow;
    float sqi = nrmI[qi * 32 + erow];
    float g = accA[e] + accB[e];
    float d = fmaxf(sqi - 2.f * g + sqj, 0.f);
    if (gi == gj) d = 0.f;
    unsigned db = __float_as_uint(d) & 0xFFFFFC00u;
    Dk[(size_t)(b * N_ + gi) * N_ + gj] = db | (unsigned)gj;
    if (offdiag)
      Tt[qj * 32 + rc][qi * 32 + erow] = db | (unsigned)gi;
  }
  if (offdiag) {
    __syncthreads();
#pragma unroll
    for (int it = 0; it < 4; ++it) {
      int u = tid + it * 256;
      int r  = u >> 4;
      int c4 = (u & 15) * 4;
      uint4 vv = *(const uint4*)&Tt[r][c4];
      *(uint4*)&Dk[(size_t)(b * N_ + tj * 64 + r) * N_ + ti * 64 + c4] = vv;
    }
  }
}

// ---------------------------------------------------------------------------
// DPP wave-min (verified round 10).
// ---------------------------------------------------------------------------
__device__ __forceinline__ unsigned wave_min_bcast(unsigned x) {
  unsigned t;
  t = (unsigned)__builtin_amdgcn_update_dpp(-1, (int)x, 0x111, 0xF, 0xF, false);
  x = min(x, t);
  t = (unsigned)__builtin_amdgcn_update_dpp(-1, (int)x, 0x112, 0xF, 0xF, false);
  x = min(x, t);
  t = (unsigned)__builtin_amdgcn_update_dpp(-1, (int)x, 0x114, 0xF, 0xF, false);
  x = min(x, t);
  t = (unsigned)__builtin_amdgcn_update_dpp(-1, (int)x, 0x118, 0xF, 0xF, false);
  x = min(x, t);
  t = (unsigned)__builtin_amdgcn_update_dpp(-1, (int)x, 0x142, 0xF, 0xF, false);
  x = min(x, t);
  t = (unsigned)__builtin_amdgcn_update_dpp(-1, (int)x, 0x143, 0xF, 0xF, false);
  x = min(x, t);
  return (unsigned)__builtin_amdgcn_readlane((int)x, 63);
}

__device__ __forceinline__ void topk_body(
    const unsigned* __restrict__ Dk, int* __restrict__ idx, int blk) {
  int w = threadIdx.x >> 6, lane = threadIdx.x & 63;
  int p = blk * 4 + w;
  const unsigned* row = Dk + (size_t)p * N_;
  unsigned key[16];
#pragma unroll
  for (int s = 0; s < 16; ++s) key[s] = row[lane + 64 * s];
  int base = p & ~(N_ - 1);
  for (int k = 0; k < KNN; ++k) {
    unsigned m = key[0];
#pragma unroll
    for (int s = 1; s < 16; ++s) m = min(m, key[s]);
    unsigned gm = wave_min_bcast(m);
    int j = (int)(gm & 1023u);
    if (lane == 0) idx[p * KNN + k] = base + j;
    if ((j & 63) == lane) key[j >> 6] = 0xFFFFFFFFu;
  }
}

// Pure topk (layer 1; transform1 lives in prelude).
__global__ __launch_bounds__(256) void topk_kernel(
    const unsigned* __restrict__ Dk, int* __restrict__ idx) {
  topk_body(Dk, idx, blockIdx.x);
}

// ---------------------------------------------------------------------------
// FUSED topk || MFMA transform (layers 2-4). Verified round 15.
// ---------------------------------------------------------------------------
template<int Cin, int Cmid>
__global__ __launch_bounds__(256) void topk_transform_kernel(
    const unsigned* __restrict__ Dk, int* __restrict__ idx,
    const float* __restrict__ X, int coff,
    const unsigned short* __restrict__ wdf, const unsigned short* __restrict__ wbf,
    const float* __restrict__ ba,
    unsigned short* __restrict__ u, unsigned short* __restrict__ v) {
  if (blockIdx.x < NP / 4) {
    topk_body(Dk, idx, blockIdx.x);
    return;
  }
  constexpr int KC = Cin / 16;
  constexpr int XB = NP / 128;
  int bx = blockIdx.x - NP / 4;
  int px = bx % XB, nt = bx / XB;
  int wv = threadIdx.x >> 6, lane = threadIdx.x & 63;
  int row = lane & 31, half = lane >> 5;
  int p0 = px * 128 + wv * 32;

  bf16x8 afr[KC];
  const float* xr = X + (size_t)(p0 + row) * 512 + coff + half * 8;
#pragma unroll
  for (int c = 0; c < KC; ++c) {
    float4 x0 = *(const float4*)(xr + c * 16);
    float4 x1 = *(const float4*)(xr + c * 16 + 4);
    union { bf16x8 vec; __hip_bfloat162 h[4]; } pk;
    pk.h[0] = __float22bfloat162_rn({x0.x, x0.y});
    pk.h[1] = __float22bfloat162_rn({x0.z, x0.w});
    pk.h[2] = __float22bfloat162_rn({x1.x, x1.y});
    pk.h[3] = __float22bfloat162_rn({x1.z, x1.w});
    afr[c] = pk.vec;
  }

  const unsigned short* wdl = wdf + ((size_t)nt * KC * 64 + lane) * 8;
  const unsigned short* wbl = wbf + ((size_t)nt * KC * 64 + lane) * 8;
  f32x16 au = {}, av = {};
#pragma unroll
  for (int c = 0; c < KC; ++c) {
    bf16x8 bd = *(const bf16x8*)(wdl + (size_t)c * 512);
    au = __builtin_amdgcn_mfma_f32_32x32x16_bf16(afr[c], bd, au, 0, 0, 0);
  }
#pragma unroll
  for (int c = 0; c < KC; ++c) {
    bf16x8 bv = *(const bf16x8*)(wbl + (size_t)c * 512);
    av = __builtin_amdgcn_mfma_f32_32x32x16_bf16(afr[c], bv, av, 0, 0, 0);
  }

  int m = nt * 32 + row;
  float bias = ba[m];
#pragma unroll
  for (int e = 0; e < 16; ++e) {
    int orow = (e & 3) + 8 * (e >> 2) + 4 * half;
    u[(size_t)(p0 + orow) * Cmid + m] = f2bf(au[e] + bias);
    v[(size_t)(p0 + orow) * Cmid + m] = f2bf(av[e]);
  }
}

// ---------------------------------------------------------------------------
// Edge MLP second GEMM + max-aggregate. Verified v1 structure (main loop
// untouched). v21: XCD-aware bijective block swizzle (T1) -- contiguous
// block chunks per XCD so each XCD's L2 holds ~2 clouds' v-rows (1 MB)
// instead of all 16 (8.4 MB > 4 MB L2). Pure index remap, speed-only.
// ---------------------------------------------------------------------------
template<int Cmid, int Cout, int CG>
__global__ __launch_bounds__(960, 3) void edge_mlp_kernel(
    const unsigned short* __restrict__ u, const unsigned short* __restrict__ v,
    const int* __restrict__ idx,
    const unsigned short* __restrict__ wbt, const float* __restrict__ bb,
    float* __restrict__ xcat, int coff) {
  constexpr int AP = Cmid + 8;
  constexpr int T  = CG / 32;
  constexpr int KC = Cmid / 16;
  constexpr int G  = Cout / CG;
  __shared__ __align__(16) unsigned short W_lds[CG * AP];
  __shared__ float qmax[120 * CG];
  int tid = threadIdx.x, w = tid >> 6, lane = tid & 63;
  int col = lane & 31, half = lane >> 5;
  int bid = xcd_swz(blockIdx.x, gridDim.x);

  int rg = bid * 480 + w * 32 + col;
  int rgc = min(rg, NP * KNN - 1);
  int p  = rgc / 20;
  int j  = idx[rgc];
  const unsigned short* up = u + (size_t)p * Cmid + half * 8;
  const unsigned short* vp = v + (size_t)j * Cmid + half * 8;

  bf16x8 afr[KC];
#pragma unroll
  for (int c = 0; c < KC; ++c) {
    union { int4 i; __hip_bfloat162 h[4]; bf16x8 vec; } U, V, R;
    U.i = *(const int4*)(up + c * 16);
    V.i = *(const int4*)(vp + c * 16);
#pragma unroll
    for (int q = 0; q < 4; ++q) {
      float2 a = __bfloat1622float2(U.h[q]);
      float2 b = __bfloat1622float2(V.h[q]);
      R.h[q] = __float22bfloat162_rn({fmaxf(a.x + b.x, 0.f), fmaxf(a.y + b.y, 0.f)});
    }
    afr[c] = R.vec;
  }

  int brow = col * AP + half * 8;

  for (int g = 0; g < G; ++g) {
    __syncthreads();
    for (int i = tid; i < CG * (Cmid / 8); i += 960) {
      int rr = i / (Cmid / 8), q = i - rr * (Cmid / 8);
      *(int4*)&W_lds[rr * AP + q * 8] =
          *(const int4*)&wbt[(size_t)(g * CG + rr) * Cmid + q * 8];
    }
    __syncthreads();
    f32x16 acc[T] = {};
#pragma unroll
    for (int c = 0; c < KC; ++c) {
#pragma unroll
      for (int t = 0; t < T; ++t) {
        bf16x8 bf = *(const bf16x8*)&W_lds[brow + t * 32 * AP + c * 16];
        acc[t] = __builtin_amdgcn_mfma_f32_32x32x16_bf16(afr[c], bf, acc[t], 0, 0, 0);
      }
    }
#pragma unroll
    for (int t = 0; t < T; ++t) {
#pragma unroll
      for (int Q = 0; Q < 4; ++Q) {
        float m0 = fmaxf(fmaxf(acc[t][4 * Q], acc[t][4 * Q + 1]),
                         fmaxf(acc[t][4 * Q + 2], acc[t][4 * Q + 3]));
        qmax[(w * 8 + 2 * Q + half) * CG + t * 32 + col] = m0;
      }
    }
    __syncthreads();
    for (int i = tid; i < 24 * CG; i += 960) {
      int pl = i / CG, c2 = i - pl * CG;
      int pg = bid * 24 + pl;
      if (pg < NP) {
        float mm = qmax[(pl * 5 + 0) * CG + c2];
#pragma unroll
        for (int qq = 1; qq < 5; ++qq) mm = fmaxf(mm, qmax[(pl * 5 + qq) * CG + c2]);
        xcat[(size_t)pg * 512 + coff + g * CG + c2] = mm + bb[g * CG + c2];
      }
    }
  }
}

// ---------------------------------------------------------------------------
// Global max pool stage 1 (verified); stage 2 fused into lin1 below.
// ---------------------------------------------------------------------------
__global__ __launch_bounds__(256) void pool1_kernel(const float* __restrict__ xcat,
                                                    float* __restrict__ part) {
  int b = blockIdx.x, g = blockIdx.y, t = threadIdx.x;
  const float* base = xcat + ((size_t)b * N_ + g * 128) * 512 + t * 2;
  float mx = -__builtin_inff(), my = -__builtin_inff();
#pragma unroll 4
  for (int r = 0; r < 128; ++r) {
    float2 vv = *(const float2*)(base + (size_t)r * 512);
    mx = fmaxf(mx, vv.x);
    my = fmaxf(my, vv.y);
  }
  *(float2*)&part[((size_t)b * 8 + g) * 512 + t * 2] = make_float2(mx, my);
}

// ---------------------------------------------------------------------------
// FUSED pool2 + lin1 (verified round 17).
// ---------------------------------------------------------------------------
__global__ __launch_bounds__(256) void pool2lin1_kernel(
    const float* __restrict__ part, const float* __restrict__ W,
    const float* __restrict__ bias, float* __restrict__ h) {
  __shared__ float pl[512];
  int flat = blockIdx.x * 256 + threadIdx.x;
  int b = flat >> 10, m = flat & 1023;
  {
    int c0 = threadIdx.x * 2;
    float2 mx = *(const float2*)&part[((size_t)b * 8 + 0) * 512 + c0];
#pragma unroll
    for (int g = 1; g < 8; ++g) {
      float2 vv = *(const float2*)&part[((size_t)b * 8 + g) * 512 + c0];
      mx.x = fmaxf(mx.x, vv.x);
      mx.y = fmaxf(mx.y, vv.y);
    }
    pl[c0] = mx.x;
    pl[c0 + 1] = mx.y;
  }
  __syncthreads();
  float s = 0.f;
  for (int c = 0; c < 512; ++c) s = fmaf(pl[c], W[(size_t)c * 1024 + m], s);
  h[flat] = s + bias[m];
}

// ---------------------------------------------------------------------------
// FUSED bn + lin2 (verified round 17).
// ---------------------------------------------------------------------------
__global__ __launch_bounds__(256) void bnlin2_kernel(
    const float* __restrict__ h, const float* __restrict__ gamma,
    const float* __restrict__ beta, const float* __restrict__ W,
    const float* __restrict__ bias, float* __restrict__ out) {
  __shared__ float h2l[1024];
  int b = blockIdx.x;
  for (int m = threadIdx.x; m < 1024; m += 256) {
    float s = 0.f;
    for (int bb = 0; bb < 16; ++bb) s += h[bb * 1024 + m];
    float mu = s * (1.f / 16.f);
    float vv = 0.f;
    for (int bb = 0; bb < 16; ++bb) {
      float d = h[bb * 1024 + m] - mu;
      vv = fmaf(d, d, vv);
    }
    vv *= (1.f / 16.f);
    float rstd = rsqrtf(vv + 1e-5f);
    float val = (h[b * 1024 + m] - mu) * (gamma[m] * rstd) + beta[m];
    h2l[m] = fmaxf(val, 0.f);
  }
  __syncthreads();
  if (threadIdx.x < 64) {
    int lane = threadIdx.x;
    float logit = 0.f;
    if (lane < 40) {
      logit = bias[lane];
      for (int c = 0; c < 1024; ++c)
        logit = fmaf(h2l[c], W[(size_t)c * 40 + lane], logit);
    }
    float mv = (lane < 40) ? logit : -__builtin_inff();
#pragma unroll
    for (int off = 32; off >= 1; off >>= 1) mv = fmaxf(mv, __shfl_xor(mv, off));
    float e = (lane < 40) ? expf(logit - mv) : 0.f;
#pragma unroll
    for (int off = 32; off >= 1; off >>= 1) e += __shfl_xor(e, off);
    float lse = mv + logf(e);
    if (lane < 40) out[b * 40 + lane] = logit - lse;
  }
}

// ---------------------------------------------------------------------------
extern "C" void kernel_launch(void* const* d_in, const int* in_sizes, int n_in,
                              void* d_out, int out_size, void* d_ws, size_t ws_size,
                              hipStream_t stream) {
  const float* pos    = (const float*)d_in[0];
  const float* W1a = (const float*)d_in[2];  const float* b1a = (const float*)d_in[3];
  const float* W1b = (const float*)d_in[4];  const float* b1b = (const float*)d_in[5];
  const float* W2a = (const float*)d_in[6];  const float* b2a = (const float*)d_in[7];
  const float* W2b = (const float*)d_in[8];  const float* b2b = (const float*)d_in[9];
  const float* W3a = (const float*)d_in[10]; const float* b3a = (const float*)d_in[11];
  const float* W3b = (const float*)d_in[12]; const float* b3b = (const float*)d_in[13];
  const float* W4a = (const float*)d_in[14]; const float* b4a = (const float*)d_in[15];
  const float* W4b = (const float*)d_in[16]; const float* b4b = (const float*)d_in[17];
  const float* lin1_w = (const float*)d_in[18]; const float* lin1_b = (const float*)d_in[19];
  const float* gamma  = (const float*)d_in[20]; const float* beta   = (const float*)d_in[21];
  const float* lin2_w = (const float*)d_in[22]; const float* lin2_b = (const float*)d_in[23];
  float* out = (float*)d_out;

  char* ws = (char*)d_ws;
  size_t off = 0;
  auto alloc = [&](size_t bytes) {
    void* p = ws + off; off += (bytes + 255) & ~(size_t)255; return p;
  };
  float*    xcat = (float*)alloc((size_t)NP * 512 * 4);   // 32 MB
  unsigned* Dk   = (unsigned*)alloc((size_t)NP * N_ * 4); // 64 MB
  unsigned short* u = (unsigned short*)alloc((size_t)NP * 256 * 2);  // 8.4 MB
  unsigned short* v = (unsigned short*)alloc((size_t)NP * 256 * 2);  // 8.4 MB
  int*      idx  = (int*)alloc((size_t)NP * KNN * 4);
  unsigned short* wbt1 = (unsigned short*)alloc(64 * 64 * 2);
  unsigned short* wbt2 = (unsigned short*)alloc(64 * 64 * 2);
  unsigned short* wbt3 = (unsigned short*)alloc(128 * 128 * 2);
  unsigned short* wbt4 = (unsigned short*)alloc(256 * 256 * 2);
  unsigned short* wd2 = (unsigned short*)alloc(64 * 64 * 2);
  unsigned short* wb2 = (unsigned short*)alloc(64 * 64 * 2);
  unsigned short* wd3 = (unsigned short*)alloc(64 * 128 * 2);
  unsigned short* wb3 = (unsigned short*)alloc(64 * 128 * 2);
  unsigned short* wd4 = (unsigned short*)alloc(128 * 256 * 2);
  unsigned short* wb4 = (unsigned short*)alloc(128 * 256 * 2);
  float* h      = (float*)alloc(16 * 1024 * 4);
  float* part   = (float*)alloc(16 * 8 * 512 * 4);

  const int EB = (NP * KNN + 479) / 480;   // 683 edge blocks
  const int TB = NP / 4;                   // 4096 topk blocks
  dim3 gt_grid(136, 1, 16);                // packed triangular (tj >= ti)

  // prelude: pairdist(C=3) || cvtall || transform1 in ONE dispatch
  prelude_kernel<<<4096, 256, 0, stream>>>(
      pos, Dk,
      W1b, W2b, W3b, W4b, wbt1, wbt2, wbt3, wbt4,
      W2a, W3a, W4a, wd2, wb2, wd3, wb3, wd4, wb4,
      W1a, b1a, u, v);
  // layer 1
  topk_kernel<<<TB, 256, 0, stream>>>(Dk, idx);
  edge_mlp_kernel<64, 64, 64><<<EB, 960, 0, stream>>>(u, v, idx, wbt1, b1b, xcat, 0);
  // layer 2
  gramt_kernel<64><<<gt_grid, 256, 0, stream>>>(xcat, 0, Dk);
  topk_transform_kernel<64, 64><<<TB + (NP / 128) * 2, 256, 0, stream>>>(
      Dk, idx, xcat, 0, wd2, wb2, b2a, u, v);
  edge_mlp_kernel<64, 64, 64><<<EB, 960, 0, stream>>>(u, v, idx, wbt2, b2b, xcat, 64);
  // layer 3
  gramt_kernel<64><<<gt_grid, 256, 0, stream>>>(xcat, 64, Dk);
  topk_transform_kernel<64, 128><<<TB + (NP / 128) * 4, 256, 0, stream>>>(
      Dk, idx, xcat, 64, wd3, wb3, b3a, u, v);
  edge_mlp_kernel<128, 128, 64><<<EB, 960, 0, stream>>>(u, v, idx, wbt3, b3b, xcat, 128);
  // layer 4
  gramt_kernel<128><<<gt_grid, 256, 0, stream>>>(xcat, 128, Dk);
  topk_transform_kernel<128, 256><<<TB + (NP / 128) * 8, 256, 0, stream>>>(
      Dk, idx, xcat, 128, wd4, wb4, b4a, u, v);
  edge_mlp_kernel<256, 256, 64><<<EB, 960, 0, stream>>>(u, v, idx, wbt4, b4b, xcat, 256);
  // head (pool1 -> pool2+lin1 -> bn+lin2)
  pool1_kernel<<<dim3(16, 8), 256, 0, stream>>>(xcat, part);
  pool2lin1_kernel<<<64, 256, 0, stream>>>(part, lin1_w, lin1_b, h);
  bnlin2_kernel<<<16, 256, 0, stream>>>(h, gamma, beta, lin2_w, lin2_b, out);
}